// Round 1
// baseline (1750.943 us; speedup 1.0000x reference)
//
#include <hip/hip_runtime.h>
#include <math.h>

static constexpr int N = 20000;   // nodes
static constexpr int E = 8192;    // hyperedges
static constexpr int F = 128;     // feature dim (in == out)

// ---------------- small helpers ----------------
__device__ __forceinline__ float gelu_erf(float x) {
    return 0.5f * x * (1.0f + erff(x * 0.70710678118654752440f));
}

// ---------------- lwT[k][f] = lin_w[f][k] ----------------
__global__ void k_transpose_lw(const float* __restrict__ lin_w, float* __restrict__ lwT) {
    int idx = blockIdx.x * 256 + threadIdx.x;
    if (idx < F * F) {
        int k = idx >> 7, f = idx & 127;
        lwT[idx] = lin_w[f * F + k];
    }
}

// ---------------- xw = x @ lin_w^T + b  (4 rows per 128-thread block) ----------------
__global__ void k_xw(const float* __restrict__ x, const float* __restrict__ lwT,
                     const float* __restrict__ lin_b, float* __restrict__ xw) {
    __shared__ __align__(16) float xs[4][F];
    int f = threadIdx.x;            // 128 threads
    int r0 = blockIdx.x * 4;
#pragma unroll
    for (int j = 0; j < 4; ++j) xs[j][f] = x[(size_t)(r0 + j) * F + f];
    __syncthreads();
    float b = lin_b[f];
    float a0 = b, a1 = b, a2 = b, a3 = b;
#pragma unroll 4
    for (int k = 0; k < F; ++k) {
        float lw = lwT[k * F + f];
        a0 += xs[0][k] * lw;
        a1 += xs[1][k] * lw;
        a2 += xs[2][k] * lw;
        a3 += xs[3][k] * lw;
    }
    xw[(size_t)(r0 + 0) * F + f] = a0;
    xw[(size_t)(r0 + 1) * F + f] = a1;
    xw[(size_t)(r0 + 2) * F + f] = a2;
    xw[(size_t)(r0 + 3) * F + f] = a3;
}

// ---------------- degrees: Dv (row sums) + De (col sums) in ONE pass over H ----------------
// grid 500 blocks x 256 threads; block b covers rows [b*40, b*40+40), all 8192 cols.
__global__ void k_deg(const float* __restrict__ H, float* __restrict__ Dv, float* __restrict__ De) {
    int tid = threadIdx.x;
    int v0 = blockIdx.x * 40;
    float4 ca[8];
#pragma unroll
    for (int j = 0; j < 8; ++j) ca[j] = make_float4(0.f, 0.f, 0.f, 0.f);
    for (int r = 0; r < 40; ++r) {
        const float* row = H + (size_t)(v0 + r) * E;
        float rs = 0.f;
#pragma unroll
        for (int j = 0; j < 8; ++j) {
            float4 vv = *reinterpret_cast<const float4*>(row + j * 1024 + tid * 4);
            ca[j].x += vv.x; ca[j].y += vv.y; ca[j].z += vv.z; ca[j].w += vv.w;
            rs += (vv.x + vv.y) + (vv.z + vv.w);
        }
#pragma unroll
        for (int off = 32; off > 0; off >>= 1) rs += __shfl_down(rs, off, 64);
        if ((tid & 63) == 0) atomicAdd(Dv + v0 + r, rs);
    }
#pragma unroll
    for (int j = 0; j < 8; ++j) {
        int c = j * 1024 + tid * 4;
        atomicAdd(De + c + 0, ca[j].x);
        atomicAdd(De + c + 1, ca[j].y);
        atomicAdd(De + c + 2, ca[j].z);
        atomicAdd(De + c + 3, ca[j].w);
    }
}

// ---------------- dvis = clip(Dv,1)^-1/2 ; se = W / clip(De,1) ----------------
__global__ void k_fin_deg(const float* __restrict__ Dv, const float* __restrict__ De,
                          const float* __restrict__ W, float* __restrict__ dvis,
                          float* __restrict__ se) {
    int i = blockIdx.x * 256 + threadIdx.x;
    if (i < N) { float d = fmaxf(Dv[i], 1.f); dvis[i] = 1.f / sqrtf(d); }
    if (i < E) { float d = fmaxf(De[i], 1.f); se[i] = W[i] / d; }
}

// ---------------- GEMM B: t[e,f] += sum_v H[v,e] * dvis[v] * xw[v,f] ----------------
// grid 640: (bx & 63) = e-tile of 128 edges, (bx >> 6) = v-chunk of 2000 rows.
__global__ __launch_bounds__(256) void k_gemmB(const float* __restrict__ H,
                                               const float* __restrict__ xw,
                                               const float* __restrict__ dvis,
                                               float* __restrict__ t) {
    __shared__ __align__(16) float As[16][128];
    __shared__ __align__(16) float Bs[16][128];
    int tid = threadIdx.x;
    int e0 = (blockIdx.x & 63) * 128;
    int vbase = (blockIdx.x >> 6) * 2000;
    int m0 = (tid & 15) * 8;
    int f0 = (tid >> 4) * 8;
    float acc[8][8] = {};

    for (int step = 0; step < 125; ++step) {
        int v0 = vbase + step * 16;
#pragma unroll
        for (int j = 0; j < 2; ++j) {
            int i4 = tid + j * 256;
            int k = i4 >> 5;
            int c = (i4 & 31) * 4;
            *reinterpret_cast<float4*>(&As[k][c]) =
                *reinterpret_cast<const float4*>(H + (size_t)(v0 + k) * E + e0 + c);
            float s = dvis[v0 + k];
            float4 b4 = *reinterpret_cast<const float4*>(xw + (size_t)(v0 + k) * F + c);
            b4.x *= s; b4.y *= s; b4.z *= s; b4.w *= s;
            *reinterpret_cast<float4*>(&Bs[k][c]) = b4;
        }
        __syncthreads();
#pragma unroll 4
        for (int kk = 0; kk < 16; ++kk) {
            float4 a0 = *reinterpret_cast<const float4*>(&As[kk][m0]);
            float4 a1 = *reinterpret_cast<const float4*>(&As[kk][m0 + 4]);
            float4 b0 = *reinterpret_cast<const float4*>(&Bs[kk][f0]);
            float4 b1 = *reinterpret_cast<const float4*>(&Bs[kk][f0 + 4]);
            float am[8] = {a0.x, a0.y, a0.z, a0.w, a1.x, a1.y, a1.z, a1.w};
            float bf[8] = {b0.x, b0.y, b0.z, b0.w, b1.x, b1.y, b1.z, b1.w};
#pragma unroll
            for (int i = 0; i < 8; ++i)
#pragma unroll
                for (int jj = 0; jj < 8; ++jj) acc[i][jj] += am[i] * bf[jj];
        }
        __syncthreads();
    }
#pragma unroll
    for (int i = 0; i < 8; ++i) {
        int e = e0 + m0 + i;
#pragma unroll
        for (int jj = 0; jj < 8; ++jj)
            atomicAdd(t + (size_t)e * F + f0 + jj, acc[i][jj]);
    }
}

// ---------------- GEMM C: C2[n,f] += sum_e H[n,e] * se[e] * t[e,f] ----------------
// grid 628: (bx % 157) = n-tile of 128 rows, (bx / 157) = e-chunk of 2048.
__global__ __launch_bounds__(256) void k_gemmC(const float* __restrict__ H,
                                               const float* __restrict__ t,
                                               const float* __restrict__ se,
                                               float* __restrict__ C2) {
    __shared__ __align__(16) float As[16][132];   // padded: transpose-staged writes
    __shared__ __align__(16) float Bs[16][128];
    int tid = threadIdx.x;
    int n0 = (blockIdx.x % 157) * 128;
    int ebase = (blockIdx.x / 157) * 2048;
    int m0 = (tid & 15) * 8;
    int f0 = (tid >> 4) * 8;
    float acc[8][8] = {};

    for (int step = 0; step < 128; ++step) {
        int e0 = ebase + step * 16;
#pragma unroll
        for (int j = 0; j < 2; ++j) {
            int i4 = tid + j * 256;
            // A tile (transposed while staging): As[k][m] = H[n0+m][e0+k]
            int m = i4 >> 2;
            int kq = (i4 & 3) * 4;
            int n = n0 + m;
            float4 hv = make_float4(0.f, 0.f, 0.f, 0.f);
            if (n < N) hv = *reinterpret_cast<const float4*>(H + (size_t)n * E + e0 + kq);
            As[kq + 0][m] = hv.x;
            As[kq + 1][m] = hv.y;
            As[kq + 2][m] = hv.z;
            As[kq + 3][m] = hv.w;
            // B tile: Bs[k][f] = se[e0+k] * t[e0+k][f]
            int k = i4 >> 5;
            int c = (i4 & 31) * 4;
            float s = se[e0 + k];
            float4 b4 = *reinterpret_cast<const float4*>(t + (size_t)(e0 + k) * F + c);
            b4.x *= s; b4.y *= s; b4.z *= s; b4.w *= s;
            *reinterpret_cast<float4*>(&Bs[k][c]) = b4;
        }
        __syncthreads();
#pragma unroll 4
        for (int kk = 0; kk < 16; ++kk) {
            float4 a0 = *reinterpret_cast<const float4*>(&As[kk][m0]);
            float4 a1 = *reinterpret_cast<const float4*>(&As[kk][m0 + 4]);
            float4 b0 = *reinterpret_cast<const float4*>(&Bs[kk][f0]);
            float4 b1 = *reinterpret_cast<const float4*>(&Bs[kk][f0 + 4]);
            float am[8] = {a0.x, a0.y, a0.z, a0.w, a1.x, a1.y, a1.z, a1.w};
            float bf[8] = {b0.x, b0.y, b0.z, b0.w, b1.x, b1.y, b1.z, b1.w};
#pragma unroll
            for (int i = 0; i < 8; ++i)
#pragma unroll
                for (int jj = 0; jj < 8; ++jj) acc[i][jj] += am[i] * bf[jj];
        }
        __syncthreads();
    }
#pragma unroll
    for (int i = 0; i < 8; ++i) {
        int n = n0 + m0 + i;
        if (n < N) {
#pragma unroll
            for (int jj = 0; jj < 8; ++jj)
                atomicAdd(C2 + (size_t)n * F + f0 + jj, acc[i][jj]);
        }
    }
}

// ---------------- out = gelu(dvis[n] * C2[n,f]) ----------------
__global__ void k_fin_out(const float* __restrict__ C2, const float* __restrict__ dvis,
                          float* __restrict__ out) {
    int i4 = blockIdx.x * 256 + threadIdx.x;   // float4 index
    if (i4 < N * F / 4) {
        int n = i4 >> 5;                        // 32 float4 per row
        float s = dvis[n];
        float4 v = reinterpret_cast<const float4*>(C2)[i4];
        float4 o;
        o.x = gelu_erf(s * v.x);
        o.y = gelu_erf(s * v.y);
        o.z = gelu_erf(s * v.z);
        o.w = gelu_erf(s * v.w);
        reinterpret_cast<float4*>(out)[i4] = o;
    }
}

extern "C" void kernel_launch(void* const* d_in, const int* in_sizes, int n_in,
                              void* d_out, int out_size, void* d_ws, size_t ws_size,
                              hipStream_t stream) {
    const float* x     = (const float*)d_in[0];
    const float* H     = (const float*)d_in[1];
    const float* W     = (const float*)d_in[2];
    const float* lin_w = (const float*)d_in[3];
    const float* lin_b = (const float*)d_in[4];
    float* out = (float*)d_out;

    // workspace layout (floats); total ~25 MB
    float* ws   = (float*)d_ws;
    float* lwT  = ws;                         // 16384
    float* xw   = lwT + 16384;                // N*F = 2,560,000
    float* Dv   = xw + (size_t)N * F;         // 20000
    float* De   = Dv + N;                     // 8192
    float* dvis = De + E;                     // 20000
    float* se   = dvis + N;                   // 8192
    float* t    = se + E;                     // E*F = 1,048,576 (16B aligned)
    float* C2   = t + (size_t)E * F;          // N*F = 2,560,000

    hipMemsetAsync(Dv, 0, (size_t)N * sizeof(float), stream);
    hipMemsetAsync(De, 0, (size_t)E * sizeof(float), stream);
    hipMemsetAsync(t, 0, (size_t)E * F * sizeof(float), stream);
    hipMemsetAsync(C2, 0, (size_t)N * F * sizeof(float), stream);

    k_transpose_lw<<<64, 256, 0, stream>>>(lin_w, lwT);
    k_xw<<<N / 4, 128, 0, stream>>>(x, lwT, lin_b, xw);
    k_deg<<<500, 256, 0, stream>>>(H, Dv, De);
    k_fin_deg<<<(N + 255) / 256, 256, 0, stream>>>(Dv, De, W, dvis, se);
    k_gemmB<<<640, 256, 0, stream>>>(H, xw, dvis, t);
    k_gemmC<<<628, 256, 0, stream>>>(H, t, se, C2);
    k_fin_out<<<(N * F / 4 + 255) / 256, 256, 0, stream>>>(C2, dvis, out);
}

// Round 2
// 875.003 us; speedup vs baseline: 2.0011x; 2.0011x over previous
//
#include <hip/hip_runtime.h>
#include <math.h>

static constexpr int N = 20000;       // nodes
static constexpr int E = 8192;        // hyperedges
static constexpr int F = 128;         // feature dim
static constexpr int NP = 20480;      // padded node count (K for gemmB)

typedef short bf16x8 __attribute__((ext_vector_type(8)));
typedef float f32x4 __attribute__((ext_vector_type(4)));

__device__ __forceinline__ float gelu_erf(float x) {
    return 0.5f * x * (1.0f + erff(x * 0.70710678118654752440f));
}
__device__ __forceinline__ ushort f2bf(float f) {
    unsigned u = __float_as_uint(f);
    return (ushort)((u + 0x7FFFu + ((u >> 16) & 1u)) >> 16);
}

// ---------------- lwT[k][f] = lin_w[f][k] ----------------
__global__ void k_transpose_lw(const float* __restrict__ lin_w, float* __restrict__ lwT) {
    int idx = blockIdx.x * 256 + threadIdx.x;
    if (idx < F * F) {
        int k = idx >> 7, f = idx & 127;
        lwT[idx] = lin_w[f * F + k];
    }
}

// ---------------- prep: one pass over H -> Dv, De, HT(bf16, [E][NP]) ----------------
// grid 320(vt) x 128(et); 64x64 tile per block.
__global__ void k_prep(const float* __restrict__ H, float* __restrict__ Dv,
                       float* __restrict__ De, ushort* __restrict__ HT) {
    __shared__ float des[64];
    __shared__ __align__(16) char tl[8192];   // 64x64 bf16, swizzled rows of 128B
    const int tid = threadIdx.x;
    const int v0 = (blockIdx.x >> 7) * 64;
    const int e0 = (blockIdx.x & 127) * 64;
    if (tid < 64) des[tid] = 0.f;
    __syncthreads();
    float4 col = make_float4(0.f, 0.f, 0.f, 0.f);
#pragma unroll
    for (int c = 0; c < 4; ++c) {
        int lin = c * 256 + tid;
        int row = lin >> 4, ch = lin & 15;     // ch constant per thread (256%16==0)
        int v = v0 + row;
        float4 hv = make_float4(0.f, 0.f, 0.f, 0.f);
        if (v < N) hv = *(const float4*)(H + (size_t)v * E + e0 + ch * 4);
        float rs = (hv.x + hv.y) + (hv.z + hv.w);
#pragma unroll
        for (int off = 1; off < 16; off <<= 1) rs += __shfl_xor(rs, off, 64);
        if ((tid & 15) == 0 && v < N) atomicAdd(Dv + v, rs);
        col.x += hv.x; col.y += hv.y; col.z += hv.z; col.w += hv.w;
        ushort4 b;
        b.x = f2bf(hv.x); b.y = f2bf(hv.y); b.z = f2bf(hv.z); b.w = f2bf(hv.w);
        int key = ((row ^ (row >> 3)) & 7) << 4;
        *(ushort4*)(tl + row * 128 + ((ch * 8) ^ key)) = b;
    }
    {
        int ch = tid & 15;
        atomicAdd(&des[ch * 4 + 0], col.x);
        atomicAdd(&des[ch * 4 + 1], col.y);
        atomicAdd(&des[ch * 4 + 2], col.z);
        atomicAdd(&des[ch * 4 + 3], col.w);
    }
    __syncthreads();
    if (tid < 64) atomicAdd(De + e0 + tid, des[tid]);
    // transpose out: HT[e][v]
#pragma unroll
    for (int c = 0; c < 2; ++c) {
        int lin = c * 256 + tid;
        int el = lin >> 3, vch = lin & 7;
        unsigned u[4];
#pragma unroll
        for (int qq = 0; qq < 4; ++qq) {
            int r1 = vch * 8 + qq * 2, r2 = r1 + 1;
            ushort a = *(const ushort*)(tl + r1 * 128 + ((el * 2) ^ (((r1 ^ (r1 >> 3)) & 7) << 4)));
            ushort b = *(const ushort*)(tl + r2 * 128 + ((el * 2) ^ (((r2 ^ (r2 >> 3)) & 7) << 4)));
            u[qq] = (unsigned)a | ((unsigned)b << 16);
        }
        uint4 o = make_uint4(u[0], u[1], u[2], u[3]);
        *(uint4*)(HT + (size_t)(e0 + el) * NP + v0 + vch * 8) = o;
    }
}

// ---------------- dvis = clip(Dv,1)^-1/2 ; se = W / clip(De,1) ----------------
__global__ void k_fin_deg(const float* __restrict__ Dv, const float* __restrict__ De,
                          const float* __restrict__ W, float* __restrict__ dvis,
                          float* __restrict__ se) {
    int i = blockIdx.x * 256 + threadIdx.x;
    if (i < N) { float d = fmaxf(Dv[i], 1.f); dvis[i] = 1.f / sqrtf(d); }
    if (i < E) { float d = fmaxf(De[i], 1.f); se[i] = W[i] / d; }
}

// ---------------- y[v][f] = bf16(dvis[v] * (x@lw^T + b)) ----------------
__global__ void k_xw(const float* __restrict__ x, const float* __restrict__ lwT,
                     const float* __restrict__ lin_b, const float* __restrict__ dvis,
                     ushort* __restrict__ y) {
    __shared__ __align__(16) float xs[4][F];
    int f = threadIdx.x;            // 128 threads
    int r0 = blockIdx.x * 4;
#pragma unroll
    for (int j = 0; j < 4; ++j) xs[j][f] = x[(size_t)(r0 + j) * F + f];
    __syncthreads();
    float b = lin_b[f];
    float a0 = b, a1 = b, a2 = b, a3 = b;
#pragma unroll 4
    for (int k = 0; k < F; ++k) {
        float lw = lwT[k * F + f];
        a0 += xs[0][k] * lw;
        a1 += xs[1][k] * lw;
        a2 += xs[2][k] * lw;
        a3 += xs[3][k] * lw;
    }
    y[(size_t)(r0 + 0) * F + f] = f2bf(dvis[r0 + 0] * a0);
    y[(size_t)(r0 + 1) * F + f] = f2bf(dvis[r0 + 1] * a1);
    y[(size_t)(r0 + 2) * F + f] = f2bf(dvis[r0 + 2] * a2);
    y[(size_t)(r0 + 3) * F + f] = f2bf(dvis[r0 + 3] * a3);
}

// ---------------- yT[f][v] = y[v][f]  (bf16 64x64 tile transpose) ----------------
__global__ void k_ytrans(const ushort* __restrict__ y, ushort* __restrict__ yT) {
    __shared__ __align__(16) char tl[8192];
    int tid = threadIdx.x;
    int r0 = (blockIdx.x >> 1) * 64;   // v
    int c0 = (blockIdx.x & 1) * 64;    // f
#pragma unroll
    for (int c = 0; c < 2; ++c) {
        int lin = c * 256 + tid;
        int row = lin >> 3, ch = lin & 7;
        uint4 v = *(const uint4*)(y + (size_t)(r0 + row) * F + c0 + ch * 8);
        int key = ((row ^ (row >> 3)) & 7) << 4;
        *(uint4*)(tl + row * 128 + ((ch * 16) ^ key)) = v;
    }
    __syncthreads();
#pragma unroll
    for (int c = 0; c < 2; ++c) {
        int lin = c * 256 + tid;
        int fl = lin >> 3, vch = lin & 7;
        unsigned u[4];
#pragma unroll
        for (int qq = 0; qq < 4; ++qq) {
            int r1 = vch * 8 + qq * 2, r2 = r1 + 1;
            ushort a = *(const ushort*)(tl + r1 * 128 + ((fl * 2) ^ (((r1 ^ (r1 >> 3)) & 7) << 4)));
            ushort b = *(const ushort*)(tl + r2 * 128 + ((fl * 2) ^ (((r2 ^ (r2 >> 3)) & 7) << 4)));
            u[qq] = (unsigned)a | ((unsigned)b << 16);
        }
        uint4 o = make_uint4(u[0], u[1], u[2], u[3]);
        *(uint4*)(yT + (size_t)(c0 + fl) * NP + r0 + vch * 8) = o;
    }
}

// ---------------- tsT[f][e] = bf16(se[e] * t[e][f]) ----------------
__global__ void k_tst(const float* __restrict__ t, const float* __restrict__ se,
                      ushort* __restrict__ tsT) {
    __shared__ __align__(16) char tl[8192];
    int tid = threadIdx.x;
    int r0 = (blockIdx.x >> 1) * 64;   // e
    int c0 = (blockIdx.x & 1) * 64;    // f
#pragma unroll
    for (int c = 0; c < 4; ++c) {
        int lin = c * 256 + tid;
        int row = lin >> 4, ch = lin & 15;
        float s = se[r0 + row];
        float4 v = *(const float4*)(t + (size_t)(r0 + row) * F + c0 + ch * 4);
        ushort4 b;
        b.x = f2bf(v.x * s); b.y = f2bf(v.y * s); b.z = f2bf(v.z * s); b.w = f2bf(v.w * s);
        int key = ((row ^ (row >> 3)) & 7) << 4;
        *(ushort4*)(tl + row * 128 + ((ch * 8) ^ key)) = b;
    }
    __syncthreads();
#pragma unroll
    for (int c = 0; c < 2; ++c) {
        int lin = c * 256 + tid;
        int fl = lin >> 3, vch = lin & 7;
        unsigned u[4];
#pragma unroll
        for (int qq = 0; qq < 4; ++qq) {
            int r1 = vch * 8 + qq * 2, r2 = r1 + 1;
            ushort a = *(const ushort*)(tl + r1 * 128 + ((fl * 2) ^ (((r1 ^ (r1 >> 3)) & 7) << 4)));
            ushort b = *(const ushort*)(tl + r2 * 128 + ((fl * 2) ^ (((r2 ^ (r2 >> 3)) & 7) << 4)));
            u[qq] = (unsigned)a | ((unsigned)b << 16);
        }
        uint4 o = make_uint4(u[0], u[1], u[2], u[3]);
        *(uint4*)(tsT + (size_t)(c0 + fl) * E + r0 + vch * 8) = o;
    }
}

// ---------------- gemmB (MFMA): t[e][f] += sum_v HT[e][v] * yT[f][v] ----------------
// grid 512: (bx&63)=m-tile of 128 edges, (bx>>6)=K-chunk of 2560 nodes (40 steps of 64).
__global__ __launch_bounds__(256) void k_gemmB(const ushort* __restrict__ HT,
                                               const ushort* __restrict__ yT,
                                               float* __restrict__ t) {
    __shared__ __align__(16) char lA[16384];   // As[m][k] 128x64 bf16, swizzled
    __shared__ __align__(16) char lB[16384];   // Bs[n][k]
    const int tid = threadIdx.x;
    const int m0 = (blockIdx.x & 63) * 128;
    const int k0 = (blockIdx.x >> 6) * 2560;
    const int lane = tid & 63, w = tid >> 6;
    const int wm = (w & 1) * 64, wn = (w >> 1) * 64;
    const int lrow = lane & 15, g16 = (lane >> 4) * 16;

    int swoff[4];
    const uint4* pA[4];
    const uint4* pB[4];
#pragma unroll
    for (int c = 0; c < 4; ++c) {
        int lin = c * 256 + tid;
        int row = lin >> 3, ch = lin & 7;
        swoff[c] = row * 128 + ((ch * 16) ^ ((row & 7) << 4));
        pA[c] = (const uint4*)(HT + (size_t)(m0 + row) * NP + k0 + ch * 8);
        pB[c] = (const uint4*)(yT + (size_t)row * NP + k0 + ch * 8);
    }
    int aoff[4][2], boff[4][2];
#pragma unroll
    for (int f = 0; f < 4; ++f)
#pragma unroll
        for (int kk = 0; kk < 2; ++kk) {
            int ma = wm + f * 16 + lrow;
            aoff[f][kk] = ma * 128 + (((kk * 64) + g16) ^ ((ma & 7) << 4));
            int nb = wn + f * 16 + lrow;
            boff[f][kk] = nb * 128 + (((kk * 64) + g16) ^ ((nb & 7) << 4));
        }

    f32x4 zero4 = {0.f, 0.f, 0.f, 0.f};
    f32x4 acc[4][4];
#pragma unroll
    for (int i = 0; i < 4; ++i)
#pragma unroll
        for (int j = 0; j < 4; ++j) acc[i][j] = zero4;

    uint4 ra[4], rb[4];
#pragma unroll
    for (int c = 0; c < 4; ++c) { ra[c] = pA[c][0]; rb[c] = pB[c][0]; }

    for (int kt = 0; kt < 40; ++kt) {
        __syncthreads();
#pragma unroll
        for (int c = 0; c < 4; ++c) {
            *(uint4*)(lA + swoff[c]) = ra[c];
            *(uint4*)(lB + swoff[c]) = rb[c];
        }
        __syncthreads();
        if (kt + 1 < 40) {
#pragma unroll
            for (int c = 0; c < 4; ++c) {
                pA[c] += 8; pB[c] += 8;
                ra[c] = pA[c][0]; rb[c] = pB[c][0];
            }
        }
#pragma unroll
        for (int kk = 0; kk < 2; ++kk) {
            bf16x8 av[4], bv[4];
#pragma unroll
            for (int f = 0; f < 4; ++f) av[f] = *(const bf16x8*)(lA + aoff[f][kk]);
#pragma unroll
            for (int f = 0; f < 4; ++f) bv[f] = *(const bf16x8*)(lB + boff[f][kk]);
#pragma unroll
            for (int i = 0; i < 4; ++i)
#pragma unroll
                for (int j = 0; j < 4; ++j)
                    acc[i][j] = __builtin_amdgcn_mfma_f32_16x16x32_bf16(av[i], bv[j], acc[i][j], 0, 0, 0);
        }
    }
    const int orow = (lane >> 4) * 4, ocol = lane & 15;
#pragma unroll
    for (int i = 0; i < 4; ++i)
#pragma unroll
        for (int j = 0; j < 4; ++j) {
            int gm = m0 + wm + i * 16 + orow;
            int gn = wn + j * 16 + ocol;
#pragma unroll
            for (int q = 0; q < 4; ++q)
                atomicAdd(t + (size_t)(gm + q) * F + gn, acc[i][j][q]);
        }
}

// ---------------- gemmC (MFMA): C2[n][f] += sum_e H[n][e] * tsT[f][e] ----------------
// A staged from fp32 H with inline bf16 conversion.
// grid 628: (bx%157)=m-tile of 128 nodes, (bx/157)=K-chunk of 2048 (32 steps of 64).
__global__ __launch_bounds__(256) void k_gemmC(const float* __restrict__ H,
                                               const ushort* __restrict__ tsT,
                                               float* __restrict__ C2) {
    __shared__ __align__(16) char lA[16384];
    __shared__ __align__(16) char lB[16384];
    const int tid = threadIdx.x;
    const int m0 = (blockIdx.x % 157) * 128;
    const int k0 = (blockIdx.x / 157) * 2048;
    const int lane = tid & 63, w = tid >> 6;
    const int wm = (w & 1) * 64, wn = (w >> 1) * 64;
    const int lrow = lane & 15, g16 = (lane >> 4) * 16;

    int awoff[8];
    bool va[8];
    const float4* pA[8];
#pragma unroll
    for (int c = 0; c < 8; ++c) {
        int lin = c * 256 + tid;
        int row = lin >> 4, ch = lin & 15;
        int gm = m0 + row;
        va[c] = gm < N;
        pA[c] = (const float4*)(H + (size_t)(va[c] ? gm : 0) * E + k0 + ch * 4);
        awoff[c] = row * 128 + ((ch * 8) ^ ((row & 7) << 4));
    }
    int bwoff[4];
    const uint4* pB[4];
#pragma unroll
    for (int c = 0; c < 4; ++c) {
        int lin = c * 256 + tid;
        int row = lin >> 3, ch = lin & 7;
        bwoff[c] = row * 128 + ((ch * 16) ^ ((row & 7) << 4));
        pB[c] = (const uint4*)(tsT + (size_t)row * E + k0 + ch * 8);
    }
    int aoff[4][2], boff[4][2];
#pragma unroll
    for (int f = 0; f < 4; ++f)
#pragma unroll
        for (int kk = 0; kk < 2; ++kk) {
            int ma = wm + f * 16 + lrow;
            aoff[f][kk] = ma * 128 + (((kk * 64) + g16) ^ ((ma & 7) << 4));
            int nb = wn + f * 16 + lrow;
            boff[f][kk] = nb * 128 + (((kk * 64) + g16) ^ ((nb & 7) << 4));
        }

    f32x4 zero4 = {0.f, 0.f, 0.f, 0.f};
    f32x4 acc[4][4];
#pragma unroll
    for (int i = 0; i < 4; ++i)
#pragma unroll
        for (int j = 0; j < 4; ++j) acc[i][j] = zero4;

    float4 ra[8];
    uint4 rb[4];
#pragma unroll
    for (int c = 0; c < 8; ++c) ra[c] = va[c] ? pA[c][0] : make_float4(0.f, 0.f, 0.f, 0.f);
#pragma unroll
    for (int c = 0; c < 4; ++c) rb[c] = pB[c][0];

    for (int kt = 0; kt < 32; ++kt) {
        __syncthreads();
#pragma unroll
        for (int c = 0; c < 8; ++c) {
            ushort4 b;
            b.x = f2bf(ra[c].x); b.y = f2bf(ra[c].y); b.z = f2bf(ra[c].z); b.w = f2bf(ra[c].w);
            *(ushort4*)(lA + awoff[c]) = b;
        }
#pragma unroll
        for (int c = 0; c < 4; ++c) *(uint4*)(lB + bwoff[c]) = rb[c];
        __syncthreads();
        if (kt + 1 < 32) {
#pragma unroll
            for (int c = 0; c < 8; ++c) {
                pA[c] += 16;
                ra[c] = va[c] ? pA[c][0] : make_float4(0.f, 0.f, 0.f, 0.f);
            }
#pragma unroll
            for (int c = 0; c < 4; ++c) { pB[c] += 8; rb[c] = pB[c][0]; }
        }
#pragma unroll
        for (int kk = 0; kk < 2; ++kk) {
            bf16x8 av[4], bv[4];
#pragma unroll
            for (int f = 0; f < 4; ++f) av[f] = *(const bf16x8*)(lA + aoff[f][kk]);
#pragma unroll
            for (int f = 0; f < 4; ++f) bv[f] = *(const bf16x8*)(lB + boff[f][kk]);
#pragma unroll
            for (int i = 0; i < 4; ++i)
#pragma unroll
                for (int j = 0; j < 4; ++j)
                    acc[i][j] = __builtin_amdgcn_mfma_f32_16x16x32_bf16(av[i], bv[j], acc[i][j], 0, 0, 0);
        }
    }
    const int orow = (lane >> 4) * 4, ocol = lane & 15;
#pragma unroll
    for (int i = 0; i < 4; ++i)
#pragma unroll
        for (int j = 0; j < 4; ++j) {
            int gm = m0 + wm + i * 16 + orow;
            int gn = wn + j * 16 + ocol;
#pragma unroll
            for (int q = 0; q < 4; ++q)
                if (gm + q < N) atomicAdd(C2 + (size_t)(gm + q) * F + gn, acc[i][j][q]);
        }
}

// ---------------- out = gelu(dvis[n] * C2[n,f]) ----------------
__global__ void k_fin_out(const float* __restrict__ C2, const float* __restrict__ dvis,
                          float* __restrict__ out) {
    int i4 = blockIdx.x * 256 + threadIdx.x;
    if (i4 < N * F / 4) {
        int n = i4 >> 5;
        float s = dvis[n];
        float4 v = reinterpret_cast<const float4*>(C2)[i4];
        float4 o;
        o.x = gelu_erf(s * v.x);
        o.y = gelu_erf(s * v.y);
        o.z = gelu_erf(s * v.z);
        o.w = gelu_erf(s * v.w);
        reinterpret_cast<float4*>(out)[i4] = o;
    }
}

extern "C" void kernel_launch(void* const* d_in, const int* in_sizes, int n_in,
                              void* d_out, int out_size, void* d_ws, size_t ws_size,
                              hipStream_t stream) {
    const float* x     = (const float*)d_in[0];
    const float* H     = (const float*)d_in[1];
    const float* W     = (const float*)d_in[2];
    const float* lin_w = (const float*)d_in[3];
    const float* lin_b = (const float*)d_in[4];
    float* out = (float*)d_out;

    // workspace layout (bytes): ~346 MiB
    char* ws = (char*)d_ws;
    ushort* HT  = (ushort*)ws;                                   // E*NP*2      = 335,544,320
    ushort* y   = (ushort*)(ws + 335544320);                     // NP*F*2      = 5,242,880
    ushort* yT  = (ushort*)(ws + 340787200);                     // F*NP*2      = 5,242,880
    float*  t   = (float*) (ws + 346030080);                     // E*F*4       = 4,194,304
    ushort* tsT = (ushort*)(ws + 350224384);                     // F*E*2       = 2,097,152
    float*  C2  = (float*) (ws + 352321536);                     // N*F*4       = 10,240,000
    float*  Dv  = (float*) (ws + 362561536);                     // N*4
    float*  dvis= (float*) (ws + 362641536);                     // N*4
    float*  De  = (float*) (ws + 362721536);                     // E*4
    float*  se  = (float*) (ws + 362754304);                     // E*4
    float*  lwT = (float*) (ws + 362787072);                     // F*F*4

    hipMemsetAsync(Dv, 0, (size_t)N * 4, stream);
    hipMemsetAsync(De, 0, (size_t)E * 4, stream);
    hipMemsetAsync(t, 0, (size_t)E * F * 4, stream);
    hipMemsetAsync(C2, 0, (size_t)N * F * 4, stream);
    // zero pad rows of y (v in [N, NP))
    hipMemsetAsync((char*)y + (size_t)N * F * 2, 0, (size_t)(NP - N) * F * 2, stream);

    k_transpose_lw<<<64, 256, 0, stream>>>(lin_w, lwT);
    k_prep<<<(NP / 64) * (E / 64), 256, 0, stream>>>(H, Dv, De, HT);
    k_fin_deg<<<(N + 255) / 256, 256, 0, stream>>>(Dv, De, W, dvis, se);
    k_xw<<<N / 4, 128, 0, stream>>>(x, lwT, lin_b, dvis, y);
    k_ytrans<<<(NP / 64) * 2, 256, 0, stream>>>(y, yT);
    k_gemmB<<<64 * 8, 256, 0, stream>>>(HT, yT, t);
    k_tst<<<(E / 64) * 2, 256, 0, stream>>>(t, se, tsT);
    k_gemmC<<<157 * 4, 256, 0, stream>>>(H, tsT, C2);
    k_fin_out<<<(N * F / 4 + 255) / 256, 256, 0, stream>>>(C2, dvis, out);
}

// Round 3
// 837.079 us; speedup vs baseline: 2.0917x; 1.0453x over previous
//
#include <hip/hip_runtime.h>
#include <math.h>

static constexpr int N = 20000;       // nodes
static constexpr int E = 8192;        // hyperedges
static constexpr int F = 128;         // feature dim
static constexpr int NP = 20480;      // padded node count (K for gemmB)

typedef short bf16x8 __attribute__((ext_vector_type(8)));
typedef float f32x4 __attribute__((ext_vector_type(4)));

__device__ __forceinline__ float gelu_erf(float x) {
    return 0.5f * x * (1.0f + erff(x * 0.70710678118654752440f));
}
__device__ __forceinline__ ushort f2bf(float f) {
    unsigned u = __float_as_uint(f);
    return (ushort)((u + 0x7FFFu + ((u >> 16) & 1u)) >> 16);
}

// ---------------- lwT[k][f] = lin_w[f][k] ----------------
__global__ void k_transpose_lw(const float* __restrict__ lin_w, float* __restrict__ lwT) {
    int idx = blockIdx.x * 256 + threadIdx.x;
    if (idx < F * F) {
        int k = idx >> 7, f = idx & 127;
        lwT[idx] = lin_w[f * F + k];
    }
}

// ---------------- prep: stream H -> Dv (direct), De (block atomics), Hb (bf16 same layout) ----
// 1250 blocks x 256 threads; 16 full rows per block.
__global__ void k_prep(const float* __restrict__ H, float* __restrict__ Dv,
                       float* __restrict__ De, ushort* __restrict__ Hb) {
    __shared__ float rp[16][4];
    const int tid = threadIdx.x, lane = tid & 63, wid = tid >> 6;
    const int r0 = blockIdx.x * 16;
    float4 ca[8];
#pragma unroll
    for (int j = 0; j < 8; ++j) ca[j] = make_float4(0.f, 0.f, 0.f, 0.f);
    for (int r = 0; r < 16; ++r) {
        const float* row = H + (size_t)(r0 + r) * E;
        ushort* orow = Hb + (size_t)(r0 + r) * E;
        float rs = 0.f;
#pragma unroll
        for (int j = 0; j < 8; ++j) {
            float4 v = *(const float4*)(row + j * 1024 + tid * 4);
            ca[j].x += v.x; ca[j].y += v.y; ca[j].z += v.z; ca[j].w += v.w;
            rs += (v.x + v.y) + (v.z + v.w);
            ushort4 b;
            b.x = f2bf(v.x); b.y = f2bf(v.y); b.z = f2bf(v.z); b.w = f2bf(v.w);
            *(ushort4*)(orow + j * 1024 + tid * 4) = b;
        }
#pragma unroll
        for (int off = 32; off > 0; off >>= 1) rs += __shfl_xor(rs, off, 64);
        if (lane == 0) rp[r][wid] = rs;
    }
    __syncthreads();
    if (tid < 16) Dv[r0 + tid] = rp[tid][0] + rp[tid][1] + rp[tid][2] + rp[tid][3];
#pragma unroll
    for (int j = 0; j < 8; ++j) {
        int c = j * 1024 + tid * 4;
        atomicAdd(De + c + 0, ca[j].x);
        atomicAdd(De + c + 1, ca[j].y);
        atomicAdd(De + c + 2, ca[j].z);
        atomicAdd(De + c + 3, ca[j].w);
    }
}

// ---------------- dvis = clip(Dv,1)^-1/2 ; se = W / clip(De,1) ----------------
__global__ void k_fin_deg(const float* __restrict__ Dv, const float* __restrict__ De,
                          const float* __restrict__ W, float* __restrict__ dvis,
                          float* __restrict__ se) {
    int i = blockIdx.x * 256 + threadIdx.x;
    if (i < N) { float d = fmaxf(Dv[i], 1.f); dvis[i] = 1.f / sqrtf(d); }
    if (i < E) { float d = fmaxf(De[i], 1.f); se[i] = W[i] / d; }
}

// ---------------- y[v][f] = bf16(dvis[v] * (x@lw^T + b)) ----------------
__global__ void k_xw(const float* __restrict__ x, const float* __restrict__ lwT,
                     const float* __restrict__ lin_b, const float* __restrict__ dvis,
                     ushort* __restrict__ y) {
    __shared__ __align__(16) float xs[4][F];
    int f = threadIdx.x;            // 128 threads
    int r0 = blockIdx.x * 4;
#pragma unroll
    for (int j = 0; j < 4; ++j) xs[j][f] = x[(size_t)(r0 + j) * F + f];
    __syncthreads();
    float b = lin_b[f];
    float a0 = b, a1 = b, a2 = b, a3 = b;
#pragma unroll 4
    for (int k = 0; k < F; ++k) {
        float lw = lwT[k * F + f];
        a0 += xs[0][k] * lw;
        a1 += xs[1][k] * lw;
        a2 += xs[2][k] * lw;
        a3 += xs[3][k] * lw;
    }
    y[(size_t)(r0 + 0) * F + f] = f2bf(dvis[r0 + 0] * a0);
    y[(size_t)(r0 + 1) * F + f] = f2bf(dvis[r0 + 1] * a1);
    y[(size_t)(r0 + 2) * F + f] = f2bf(dvis[r0 + 2] * a2);
    y[(size_t)(r0 + 3) * F + f] = f2bf(dvis[r0 + 3] * a3);
}

// ---------------- yT[f][v] = y[v][f]  (bf16 64x64 tile transpose) ----------------
__global__ void k_ytrans(const ushort* __restrict__ y, ushort* __restrict__ yT) {
    __shared__ __align__(16) char tl[8192];
    int tid = threadIdx.x;
    int r0 = (blockIdx.x >> 1) * 64;   // v
    int c0 = (blockIdx.x & 1) * 64;    // f
#pragma unroll
    for (int c = 0; c < 2; ++c) {
        int lin = c * 256 + tid;
        int row = lin >> 3, ch = lin & 7;
        uint4 v = *(const uint4*)(y + (size_t)(r0 + row) * F + c0 + ch * 8);
        int key = ((row ^ (row >> 3)) & 7) << 4;
        *(uint4*)(tl + row * 128 + ((ch * 16) ^ key)) = v;
    }
    __syncthreads();
#pragma unroll
    for (int c = 0; c < 2; ++c) {
        int lin = c * 256 + tid;
        int fl = lin >> 3, vch = lin & 7;
        unsigned u[4];
#pragma unroll
        for (int qq = 0; qq < 4; ++qq) {
            int r1 = vch * 8 + qq * 2, r2 = r1 + 1;
            ushort a = *(const ushort*)(tl + r1 * 128 + ((fl * 2) ^ (((r1 ^ (r1 >> 3)) & 7) << 4)));
            ushort b = *(const ushort*)(tl + r2 * 128 + ((fl * 2) ^ (((r2 ^ (r2 >> 3)) & 7) << 4)));
            u[qq] = (unsigned)a | ((unsigned)b << 16);
        }
        uint4 o = make_uint4(u[0], u[1], u[2], u[3]);
        *(uint4*)(yT + (size_t)(c0 + fl) * NP + r0 + vch * 8) = o;
    }
}

// ---------------- tsT[f][e] = bf16(se[e] * t[e][f]) ----------------
__global__ void k_tst(const float* __restrict__ t, const float* __restrict__ se,
                      ushort* __restrict__ tsT) {
    __shared__ __align__(16) char tl[8192];
    int tid = threadIdx.x;
    int r0 = (blockIdx.x >> 1) * 64;   // e
    int c0 = (blockIdx.x & 1) * 64;    // f
#pragma unroll
    for (int c = 0; c < 4; ++c) {
        int lin = c * 256 + tid;
        int row = lin >> 4, ch = lin & 15;
        float s = se[r0 + row];
        float4 v = *(const float4*)(t + (size_t)(r0 + row) * F + c0 + ch * 4);
        ushort4 b;
        b.x = f2bf(v.x * s); b.y = f2bf(v.y * s); b.z = f2bf(v.z * s); b.w = f2bf(v.w * s);
        int key = ((row ^ (row >> 3)) & 7) << 4;
        *(ushort4*)(tl + row * 128 + ((ch * 8) ^ key)) = b;
    }
    __syncthreads();
#pragma unroll
    for (int c = 0; c < 2; ++c) {
        int lin = c * 256 + tid;
        int fl = lin >> 3, vch = lin & 7;
        unsigned u[4];
#pragma unroll
        for (int qq = 0; qq < 4; ++qq) {
            int r1 = vch * 8 + qq * 2, r2 = r1 + 1;
            ushort a = *(const ushort*)(tl + r1 * 128 + ((fl * 2) ^ (((r1 ^ (r1 >> 3)) & 7) << 4)));
            ushort b = *(const ushort*)(tl + r2 * 128 + ((fl * 2) ^ (((r2 ^ (r2 >> 3)) & 7) << 4)));
            u[qq] = (unsigned)a | ((unsigned)b << 16);
        }
        uint4 o = make_uint4(u[0], u[1], u[2], u[3]);
        *(uint4*)(tsT + (size_t)(c0 + fl) * E + r0 + vch * 8) = o;
    }
}

// ---------------- gemmB (MFMA): t[e][f] += sum_v Hb[v][e] * yT[f][v] ----------------
// A = H^T staged via in-LDS transpose from Hb[v][e].
// grid 512: (bx&63)=e-tile of 128, (bx>>6)=v-chunk of 2560 (40 steps of 64).
__global__ __launch_bounds__(256) void k_gemmB(const ushort* __restrict__ Hb,
                                               const ushort* __restrict__ yT,
                                               float* __restrict__ t) {
    __shared__ __align__(16) char lA[16384];   // As[e 128][v 64] bf16, key ((e>>3)&7)<<4
    __shared__ __align__(16) char lB[16384];   // Bs[f 128][v 64] bf16, key (f&7)<<4
    const int tid = threadIdx.x;
    const int m0 = (blockIdx.x & 63) * 128;    // e tile
    const int k0 = (blockIdx.x >> 6) * 2560;   // v chunk
    const int lane = tid & 63, w = tid >> 6;
    const int wm = (w & 1) * 64, wn = (w >> 1) * 64;
    const int lrow = lane & 15, g16 = (lane >> 4) * 16;

    // A staging: thread owns v-quad vq = tid>>4 (4 rows) x e-octet e8 = (tid&15)*8
    const int vq = tid >> 4;
    const int e8 = (tid & 15) * 8;
    const ushort* pa = Hb + (size_t)(k0 + vq * 4) * E + m0 + e8;
    const int abase = e8 * 128 + ((vq * 8) ^ ((tid & 7) << 4));

    // B staging: straight copy, 4 x uint4
    int bwoff[4];
    const uint4* pb[4];
#pragma unroll
    for (int c = 0; c < 4; ++c) {
        int lin = c * 256 + tid;
        int row = lin >> 3, ch = lin & 7;
        bwoff[c] = row * 128 + ((ch * 16) ^ ((row & 7) << 4));
        pb[c] = (const uint4*)(yT + (size_t)row * NP + k0 + ch * 8);
    }
    int aoff[4][2], boff[4][2];
#pragma unroll
    for (int f = 0; f < 4; ++f)
#pragma unroll
        for (int kk = 0; kk < 2; ++kk) {
            int ma = wm + f * 16 + lrow;
            aoff[f][kk] = ma * 128 + (((kk * 64) + g16) ^ (((ma >> 3) & 7) << 4));
            int nb = wn + f * 16 + lrow;
            boff[f][kk] = nb * 128 + (((kk * 64) + g16) ^ ((nb & 7) << 4));
        }

    f32x4 zero4 = {0.f, 0.f, 0.f, 0.f};
    f32x4 acc[4][4];
#pragma unroll
    for (int i = 0; i < 4; ++i)
#pragma unroll
        for (int j = 0; j < 4; ++j) acc[i][j] = zero4;

    uint4 ra[4], rb[4];
#pragma unroll
    for (int r = 0; r < 4; ++r) ra[r] = *(const uint4*)(pa + (size_t)r * E);
#pragma unroll
    for (int c = 0; c < 4; ++c) rb[c] = pb[c][0];

    for (int kt = 0; kt < 40; ++kt) {
        __syncthreads();
        {
            const ushort* u0 = (const ushort*)&ra[0];
            const ushort* u1 = (const ushort*)&ra[1];
            const ushort* u2 = (const ushort*)&ra[2];
            const ushort* u3 = (const ushort*)&ra[3];
#pragma unroll
            for (int i = 0; i < 8; ++i) {
                uint2 wv;
                wv.x = (unsigned)u0[i] | ((unsigned)u1[i] << 16);
                wv.y = (unsigned)u2[i] | ((unsigned)u3[i] << 16);
                *(uint2*)(lA + abase + i * 128) = wv;
            }
        }
#pragma unroll
        for (int c = 0; c < 4; ++c) *(uint4*)(lB + bwoff[c]) = rb[c];
        __syncthreads();
        if (kt + 1 < 40) {
            pa += (size_t)64 * E;
#pragma unroll
            for (int r = 0; r < 4; ++r) ra[r] = *(const uint4*)(pa + (size_t)r * E);
#pragma unroll
            for (int c = 0; c < 4; ++c) { pb[c] += 8; rb[c] = pb[c][0]; }
        }
#pragma unroll
        for (int kk = 0; kk < 2; ++kk) {
            bf16x8 av[4], bv[4];
#pragma unroll
            for (int f = 0; f < 4; ++f) av[f] = *(const bf16x8*)(lA + aoff[f][kk]);
#pragma unroll
            for (int f = 0; f < 4; ++f) bv[f] = *(const bf16x8*)(lB + boff[f][kk]);
#pragma unroll
            for (int i = 0; i < 4; ++i)
#pragma unroll
                for (int j = 0; j < 4; ++j)
                    acc[i][j] = __builtin_amdgcn_mfma_f32_16x16x32_bf16(av[i], bv[j], acc[i][j], 0, 0, 0);
        }
    }
    const int orow = (lane >> 4) * 4, ocol = lane & 15;
#pragma unroll
    for (int i = 0; i < 4; ++i)
#pragma unroll
        for (int j = 0; j < 4; ++j) {
            int gm = m0 + wm + i * 16 + orow;
            int gn = wn + j * 16 + ocol;
#pragma unroll
            for (int q = 0; q < 4; ++q)
                atomicAdd(t + (size_t)(gm + q) * F + gn, acc[i][j][q]);
        }
}

// ---------------- gemmC (MFMA): C2[n][f] += sum_e Hb[n][e] * tsT[f][e] ----------------
// grid 628: (bx%157)=n-tile of 128, (bx/157)=e-chunk of 2048 (32 steps of 64).
__global__ __launch_bounds__(256) void k_gemmC(const ushort* __restrict__ Hb,
                                               const ushort* __restrict__ tsT,
                                               float* __restrict__ C2) {
    __shared__ __align__(16) char lA[16384];
    __shared__ __align__(16) char lB[16384];
    const int tid = threadIdx.x;
    const int m0 = (blockIdx.x % 157) * 128;
    const int k0 = (blockIdx.x / 157) * 2048;
    const int lane = tid & 63, w = tid >> 6;
    const int wm = (w & 1) * 64, wn = (w >> 1) * 64;
    const int lrow = lane & 15, g16 = (lane >> 4) * 16;

    int awoff[4], bwoff[4];
    const uint4* pA[4];
    const uint4* pB[4];
#pragma unroll
    for (int c = 0; c < 4; ++c) {
        int lin = c * 256 + tid;
        int row = lin >> 3, ch = lin & 7;
        awoff[c] = row * 128 + ((ch * 16) ^ ((row & 7) << 4));
        bwoff[c] = awoff[c];
        pA[c] = (const uint4*)(Hb + (size_t)(m0 + row) * E + k0 + ch * 8);
        pB[c] = (const uint4*)(tsT + (size_t)row * E + k0 + ch * 8);
    }
    int aoff[4][2], boff[4][2];
#pragma unroll
    for (int f = 0; f < 4; ++f)
#pragma unroll
        for (int kk = 0; kk < 2; ++kk) {
            int ma = wm + f * 16 + lrow;
            aoff[f][kk] = ma * 128 + (((kk * 64) + g16) ^ ((ma & 7) << 4));
            int nb = wn + f * 16 + lrow;
            boff[f][kk] = nb * 128 + (((kk * 64) + g16) ^ ((nb & 7) << 4));
        }

    f32x4 zero4 = {0.f, 0.f, 0.f, 0.f};
    f32x4 acc[4][4];
#pragma unroll
    for (int i = 0; i < 4; ++i)
#pragma unroll
        for (int j = 0; j < 4; ++j) acc[i][j] = zero4;

    uint4 ra[4], rb[4];
#pragma unroll
    for (int c = 0; c < 4; ++c) { ra[c] = pA[c][0]; rb[c] = pB[c][0]; }

    for (int kt = 0; kt < 32; ++kt) {
        __syncthreads();
#pragma unroll
        for (int c = 0; c < 4; ++c) {
            *(uint4*)(lA + awoff[c]) = ra[c];
            *(uint4*)(lB + bwoff[c]) = rb[c];
        }
        __syncthreads();
        if (kt + 1 < 32) {
#pragma unroll
            for (int c = 0; c < 4; ++c) {
                pA[c] += 8; pB[c] += 8;
                ra[c] = pA[c][0]; rb[c] = pB[c][0];
            }
        }
#pragma unroll
        for (int kk = 0; kk < 2; ++kk) {
            bf16x8 av[4], bv[4];
#pragma unroll
            for (int f = 0; f < 4; ++f) av[f] = *(const bf16x8*)(lA + aoff[f][kk]);
#pragma unroll
            for (int f = 0; f < 4; ++f) bv[f] = *(const bf16x8*)(lB + boff[f][kk]);
#pragma unroll
            for (int i = 0; i < 4; ++i)
#pragma unroll
                for (int j = 0; j < 4; ++j)
                    acc[i][j] = __builtin_amdgcn_mfma_f32_16x16x32_bf16(av[i], bv[j], acc[i][j], 0, 0, 0);
        }
    }
    const int orow = (lane >> 4) * 4, ocol = lane & 15;
#pragma unroll
    for (int i = 0; i < 4; ++i)
#pragma unroll
        for (int j = 0; j < 4; ++j) {
            int gm = m0 + wm + i * 16 + orow;
            int gn = wn + j * 16 + ocol;
#pragma unroll
            for (int q = 0; q < 4; ++q)
                if (gm + q < N) atomicAdd(C2 + (size_t)(gm + q) * F + gn, acc[i][j][q]);
        }
}

// ---------------- out = gelu(dvis[n] * C2[n,f]) ----------------
__global__ void k_fin_out(const float* __restrict__ C2, const float* __restrict__ dvis,
                          float* __restrict__ out) {
    int i4 = blockIdx.x * 256 + threadIdx.x;
    if (i4 < N * F / 4) {
        int n = i4 >> 5;
        float s = dvis[n];
        float4 v = reinterpret_cast<const float4*>(C2)[i4];
        float4 o;
        o.x = gelu_erf(s * v.x);
        o.y = gelu_erf(s * v.y);
        o.z = gelu_erf(s * v.z);
        o.w = gelu_erf(s * v.w);
        reinterpret_cast<float4*>(out)[i4] = o;
    }
}

extern "C" void kernel_launch(void* const* d_in, const int* in_sizes, int n_in,
                              void* d_out, int out_size, void* d_ws, size_t ws_size,
                              hipStream_t stream) {
    const float* x     = (const float*)d_in[0];
    const float* H     = (const float*)d_in[1];
    const float* W     = (const float*)d_in[2];
    const float* lin_w = (const float*)d_in[3];
    const float* lin_b = (const float*)d_in[4];
    float* out = (float*)d_out;

    // workspace layout (bytes): ~346 MiB
    char* ws = (char*)d_ws;
    ushort* Hb  = (ushort*)ws;                                   // NP*E*2      = 335,544,320
    ushort* y   = (ushort*)(ws + 335544320);                     // NP*F*2      = 5,242,880
    ushort* yT  = (ushort*)(ws + 340787200);                     // F*NP*2      = 5,242,880
    float*  t   = (float*) (ws + 346030080);                     // E*F*4       = 4,194,304
    ushort* tsT = (ushort*)(ws + 350224384);                     // F*E*2       = 2,097,152
    float*  C2  = (float*) (ws + 352321536);                     // N*F*4       = 10,240,000
    float*  Dv  = (float*) (ws + 362561536);                     // N*4
    float*  dvis= (float*) (ws + 362641536);                     // N*4
    float*  De  = (float*) (ws + 362721536);                     // E*4
    float*  se  = (float*) (ws + 362754304);                     // E*4
    float*  lwT = (float*) (ws + 362787072);                     // F*F*4

    hipMemsetAsync(De, 0, (size_t)E * 4, stream);
    hipMemsetAsync(t, 0, (size_t)E * F * 4, stream);
    hipMemsetAsync(C2, 0, (size_t)N * F * 4, stream);
    // zero pads: Hb rows [N, NP), y rows [N, NP)
    hipMemsetAsync((char*)Hb + (size_t)N * E * 2, 0, (size_t)(NP - N) * E * 2, stream);
    hipMemsetAsync((char*)y + (size_t)N * F * 2, 0, (size_t)(NP - N) * F * 2, stream);

    k_transpose_lw<<<64, 256, 0, stream>>>(lin_w, lwT);
    k_prep<<<N / 16, 256, 0, stream>>>(H, Dv, De, Hb);
    k_fin_deg<<<(N + 255) / 256, 256, 0, stream>>>(Dv, De, W, dvis, se);
    k_xw<<<N / 4, 128, 0, stream>>>(x, lwT, lin_b, dvis, y);
    k_ytrans<<<(NP / 64) * 2, 256, 0, stream>>>(y, yT);
    k_gemmB<<<64 * 8, 256, 0, stream>>>(Hb, yT, t);
    k_tst<<<(E / 64) * 2, 256, 0, stream>>>(t, se, tsT);
    k_gemmC<<<157 * 4, 256, 0, stream>>>(Hb, tsT, C2);
    k_fin_out<<<(N * F / 4 + 255) / 256, 256, 0, stream>>>(C2, dvis, out);
}

// Round 4
// 721.720 us; speedup vs baseline: 2.4261x; 1.1598x over previous
//
#include <hip/hip_runtime.h>
#include <math.h>

static constexpr int N = 20000;       // nodes
static constexpr int E = 8192;        // hyperedges
static constexpr int F = 128;         // feature dim
static constexpr int NP = 20480;      // padded node count (K for gemmB)
static constexpr int NP2 = 20096;     // padded node count for gemmC output planes (157*128)
static constexpr int PREP_BLOCKS = 500;   // 40 rows each
static constexpr int KS_B = 8;        // gemmB split-K
static constexpr int KS_C = 4;        // gemmC split-K

typedef short bf16x8 __attribute__((ext_vector_type(8)));
typedef float f32x4 __attribute__((ext_vector_type(4)));

__device__ __forceinline__ float gelu_erf(float x) {
    return 0.5f * x * (1.0f + erff(x * 0.70710678118654752440f));
}
__device__ __forceinline__ ushort f2bf(float f) {
    unsigned u = __float_as_uint(f);
    return (ushort)((u + 0x7FFFu + ((u >> 16) & 1u)) >> 16);
}

// ---------------- lwT[k][f] = lin_w[f][k] ----------------
__global__ void k_transpose_lw(const float* __restrict__ lin_w, float* __restrict__ lwT) {
    int idx = blockIdx.x * 256 + threadIdx.x;
    if (idx < F * F) {
        int k = idx >> 7, f = idx & 127;
        lwT[idx] = lin_w[f * F + k];
    }
}

// ---------------- prep: stream H -> Dv (direct), DeP (per-block col partials), Hb ----------
// 500 blocks x 256 threads; 40 full rows per block. NO atomics.
__global__ void k_prep(const float* __restrict__ H, float* __restrict__ Dv,
                       float* __restrict__ DeP, ushort* __restrict__ Hb) {
    __shared__ float rp[40][4];
    const int tid = threadIdx.x, lane = tid & 63, wid = tid >> 6;
    const int r0 = blockIdx.x * 40;
    float4 ca[8];
#pragma unroll
    for (int j = 0; j < 8; ++j) ca[j] = make_float4(0.f, 0.f, 0.f, 0.f);
    for (int r = 0; r < 40; ++r) {
        const float* row = H + (size_t)(r0 + r) * E;
        ushort* orow = Hb + (size_t)(r0 + r) * E;
        float rs = 0.f;
#pragma unroll
        for (int j = 0; j < 8; ++j) {
            float4 v = *(const float4*)(row + j * 1024 + tid * 4);
            ca[j].x += v.x; ca[j].y += v.y; ca[j].z += v.z; ca[j].w += v.w;
            rs += (v.x + v.y) + (v.z + v.w);
            ushort4 b;
            b.x = f2bf(v.x); b.y = f2bf(v.y); b.z = f2bf(v.z); b.w = f2bf(v.w);
            *(ushort4*)(orow + j * 1024 + tid * 4) = b;
        }
#pragma unroll
        for (int off = 32; off > 0; off >>= 1) rs += __shfl_xor(rs, off, 64);
        if (lane == 0) rp[r][wid] = rs;
    }
    __syncthreads();
    if (tid < 40) Dv[r0 + tid] = rp[tid][0] + rp[tid][1] + rp[tid][2] + rp[tid][3];
    float* dp = DeP + (size_t)blockIdx.x * E;
#pragma unroll
    for (int j = 0; j < 8; ++j) *(float4*)(dp + j * 1024 + tid * 4) = ca[j];
}

// ---------------- dvis = clip(Dv,1)^-1/2 ; se = W / clip(sum DeP,1) ----------------
__global__ void k_fin_deg(const float* __restrict__ Dv, const float* __restrict__ DeP,
                          const float* __restrict__ W, float* __restrict__ dvis,
                          float* __restrict__ se) {
    int i = blockIdx.x * 256 + threadIdx.x;
    if (i < N) { float d = fmaxf(Dv[i], 1.f); dvis[i] = 1.f / sqrtf(d); }
    if (i < E) {
        float s = 0.f;
        for (int p = 0; p < PREP_BLOCKS; ++p) s += DeP[(size_t)p * E + i];
        se[i] = W[i] / fmaxf(s, 1.f);
    }
}

// ---------------- y[v][f] = bf16(dvis[v] * (x@lw^T + b)) ----------------
__global__ void k_xw(const float* __restrict__ x, const float* __restrict__ lwT,
                     const float* __restrict__ lin_b, const float* __restrict__ dvis,
                     ushort* __restrict__ y) {
    __shared__ __align__(16) float xs[4][F];
    int f = threadIdx.x;            // 128 threads
    int r0 = blockIdx.x * 4;
#pragma unroll
    for (int j = 0; j < 4; ++j) xs[j][f] = x[(size_t)(r0 + j) * F + f];
    __syncthreads();
    float b = lin_b[f];
    float a0 = b, a1 = b, a2 = b, a3 = b;
#pragma unroll 4
    for (int k = 0; k < F; ++k) {
        float lw = lwT[k * F + f];
        a0 += xs[0][k] * lw;
        a1 += xs[1][k] * lw;
        a2 += xs[2][k] * lw;
        a3 += xs[3][k] * lw;
    }
    y[(size_t)(r0 + 0) * F + f] = f2bf(dvis[r0 + 0] * a0);
    y[(size_t)(r0 + 1) * F + f] = f2bf(dvis[r0 + 1] * a1);
    y[(size_t)(r0 + 2) * F + f] = f2bf(dvis[r0 + 2] * a2);
    y[(size_t)(r0 + 3) * F + f] = f2bf(dvis[r0 + 3] * a3);
}

// ---------------- yT[f][v] = y[v][f]  (bf16 64x64 tile transpose) ----------------
__global__ void k_ytrans(const ushort* __restrict__ y, ushort* __restrict__ yT) {
    __shared__ __align__(16) char tl[8192];
    int tid = threadIdx.x;
    int r0 = (blockIdx.x >> 1) * 64;   // v
    int c0 = (blockIdx.x & 1) * 64;    // f
#pragma unroll
    for (int c = 0; c < 2; ++c) {
        int lin = c * 256 + tid;
        int row = lin >> 3, ch = lin & 7;
        uint4 v = *(const uint4*)(y + (size_t)(r0 + row) * F + c0 + ch * 8);
        int key = ((row ^ (row >> 3)) & 7) << 4;
        *(uint4*)(tl + row * 128 + ((ch * 16) ^ key)) = v;
    }
    __syncthreads();
#pragma unroll
    for (int c = 0; c < 2; ++c) {
        int lin = c * 256 + tid;
        int fl = lin >> 3, vch = lin & 7;
        unsigned u[4];
#pragma unroll
        for (int qq = 0; qq < 4; ++qq) {
            int r1 = vch * 8 + qq * 2, r2 = r1 + 1;
            ushort a = *(const ushort*)(tl + r1 * 128 + ((fl * 2) ^ (((r1 ^ (r1 >> 3)) & 7) << 4)));
            ushort b = *(const ushort*)(tl + r2 * 128 + ((fl * 2) ^ (((r2 ^ (r2 >> 3)) & 7) << 4)));
            u[qq] = (unsigned)a | ((unsigned)b << 16);
        }
        uint4 o = make_uint4(u[0], u[1], u[2], u[3]);
        *(uint4*)(yT + (size_t)(c0 + fl) * NP + r0 + vch * 8) = o;
    }
}

// ---------------- tsT[f][e] = bf16(se[e] * sum_ks tB[ks][e][f])  (reduce + transpose) ------
__global__ void k_tst(const float* __restrict__ tB, const float* __restrict__ se,
                      ushort* __restrict__ tsT) {
    __shared__ __align__(16) char tl[8192];
    int tid = threadIdx.x;
    int r0 = (blockIdx.x >> 1) * 64;   // e
    int c0 = (blockIdx.x & 1) * 64;    // f
#pragma unroll
    for (int c = 0; c < 4; ++c) {
        int lin = c * 256 + tid;
        int row = lin >> 4, ch = lin & 15;
        size_t base = (size_t)(r0 + row) * F + c0 + ch * 4;
        float4 v = make_float4(0.f, 0.f, 0.f, 0.f);
#pragma unroll
        for (int ks = 0; ks < KS_B; ++ks) {
            float4 p = *(const float4*)(tB + (size_t)ks * E * F + base);
            v.x += p.x; v.y += p.y; v.z += p.z; v.w += p.w;
        }
        float s = se[r0 + row];
        ushort4 b;
        b.x = f2bf(v.x * s); b.y = f2bf(v.y * s); b.z = f2bf(v.z * s); b.w = f2bf(v.w * s);
        int key = ((row ^ (row >> 3)) & 7) << 4;
        *(ushort4*)(tl + row * 128 + ((ch * 8) ^ key)) = b;
    }
    __syncthreads();
#pragma unroll
    for (int c = 0; c < 2; ++c) {
        int lin = c * 256 + tid;
        int fl = lin >> 3, vch = lin & 7;
        unsigned u[4];
#pragma unroll
        for (int qq = 0; qq < 4; ++qq) {
            int r1 = vch * 8 + qq * 2, r2 = r1 + 1;
            ushort a = *(const ushort*)(tl + r1 * 128 + ((fl * 2) ^ (((r1 ^ (r1 >> 3)) & 7) << 4)));
            ushort b = *(const ushort*)(tl + r2 * 128 + ((fl * 2) ^ (((r2 ^ (r2 >> 3)) & 7) << 4)));
            u[qq] = (unsigned)a | ((unsigned)b << 16);
        }
        uint4 o = make_uint4(u[0], u[1], u[2], u[3]);
        *(uint4*)(tsT + (size_t)(c0 + fl) * E + r0 + vch * 8) = o;
    }
}

// ---------------- gemmB (MFMA): tB[ks][e][f] = sum_{v in chunk} Hb[v][e] * yT[f][v] -------
// grid 512: (bx&63)=e-tile of 128, ks=(bx>>6)=v-chunk of 2560 (40 steps of 64). Direct store.
__global__ __launch_bounds__(256) void k_gemmB(const ushort* __restrict__ Hb,
                                               const ushort* __restrict__ yT,
                                               float* __restrict__ tB) {
    __shared__ __align__(16) char lA[16384];   // As[e 128][v 64] bf16, key ((e>>3)&7)<<4
    __shared__ __align__(16) char lB[16384];   // Bs[f 128][v 64] bf16, key (f&7)<<4
    const int tid = threadIdx.x;
    const int m0 = (blockIdx.x & 63) * 128;    // e tile
    const int ks = blockIdx.x >> 6;
    const int k0 = ks * 2560;                  // v chunk
    const int lane = tid & 63, w = tid >> 6;
    const int wm = (w & 1) * 64, wn = (w >> 1) * 64;
    const int lrow = lane & 15, g16 = (lane >> 4) * 16;

    const int vq = tid >> 4;
    const int e8 = (tid & 15) * 8;
    const ushort* pa = Hb + (size_t)(k0 + vq * 4) * E + m0 + e8;
    const int abase = e8 * 128 + ((vq * 8) ^ ((tid & 7) << 4));

    int bwoff[4];
    const uint4* pb[4];
#pragma unroll
    for (int c = 0; c < 4; ++c) {
        int lin = c * 256 + tid;
        int row = lin >> 3, ch = lin & 7;
        bwoff[c] = row * 128 + ((ch * 16) ^ ((row & 7) << 4));
        pb[c] = (const uint4*)(yT + (size_t)row * NP + k0 + ch * 8);
    }
    int aoff[4][2], boff[4][2];
#pragma unroll
    for (int f = 0; f < 4; ++f)
#pragma unroll
        for (int kk = 0; kk < 2; ++kk) {
            int ma = wm + f * 16 + lrow;
            aoff[f][kk] = ma * 128 + (((kk * 64) + g16) ^ (((ma >> 3) & 7) << 4));
            int nb = wn + f * 16 + lrow;
            boff[f][kk] = nb * 128 + (((kk * 64) + g16) ^ ((nb & 7) << 4));
        }

    f32x4 zero4 = {0.f, 0.f, 0.f, 0.f};
    f32x4 acc[4][4];
#pragma unroll
    for (int i = 0; i < 4; ++i)
#pragma unroll
        for (int j = 0; j < 4; ++j) acc[i][j] = zero4;

    uint4 ra[4], rb[4];
#pragma unroll
    for (int r = 0; r < 4; ++r) ra[r] = *(const uint4*)(pa + (size_t)r * E);
#pragma unroll
    for (int c = 0; c < 4; ++c) rb[c] = pb[c][0];

    for (int kt = 0; kt < 40; ++kt) {
        __syncthreads();
        {
            const ushort* u0 = (const ushort*)&ra[0];
            const ushort* u1 = (const ushort*)&ra[1];
            const ushort* u2 = (const ushort*)&ra[2];
            const ushort* u3 = (const ushort*)&ra[3];
#pragma unroll
            for (int i = 0; i < 8; ++i) {
                uint2 wv;
                wv.x = (unsigned)u0[i] | ((unsigned)u1[i] << 16);
                wv.y = (unsigned)u2[i] | ((unsigned)u3[i] << 16);
                *(uint2*)(lA + abase + i * 128) = wv;
            }
        }
#pragma unroll
        for (int c = 0; c < 4; ++c) *(uint4*)(lB + bwoff[c]) = rb[c];
        __syncthreads();
        if (kt + 1 < 40) {
            pa += (size_t)64 * E;
#pragma unroll
            for (int r = 0; r < 4; ++r) ra[r] = *(const uint4*)(pa + (size_t)r * E);
#pragma unroll
            for (int c = 0; c < 4; ++c) { pb[c] += 8; rb[c] = pb[c][0]; }
        }
#pragma unroll
        for (int kk = 0; kk < 2; ++kk) {
            bf16x8 av[4], bv[4];
#pragma unroll
            for (int f = 0; f < 4; ++f) av[f] = *(const bf16x8*)(lA + aoff[f][kk]);
#pragma unroll
            for (int f = 0; f < 4; ++f) bv[f] = *(const bf16x8*)(lB + boff[f][kk]);
#pragma unroll
            for (int i = 0; i < 4; ++i)
#pragma unroll
                for (int j = 0; j < 4; ++j)
                    acc[i][j] = __builtin_amdgcn_mfma_f32_16x16x32_bf16(av[i], bv[j], acc[i][j], 0, 0, 0);
        }
    }
    float* plane = tB + (size_t)ks * E * F;
    const int orow = (lane >> 4) * 4, ocol = lane & 15;
#pragma unroll
    for (int i = 0; i < 4; ++i)
#pragma unroll
        for (int j = 0; j < 4; ++j) {
            int gm = m0 + wm + i * 16 + orow;
            int gn = wn + j * 16 + ocol;
#pragma unroll
            for (int q = 0; q < 4; ++q)
                plane[(size_t)(gm + q) * F + gn] = acc[i][j][q];
        }
}

// ---------------- gemmC (MFMA): C2P[ks][n][f] = sum_{e in chunk} Hb[n][e] * tsT[f][e] ------
// grid 628: (bx%157)=n-tile of 128, ks=(bx/157)=e-chunk of 2048 (32 steps of 64). Direct store.
__global__ __launch_bounds__(256) void k_gemmC(const ushort* __restrict__ Hb,
                                               const ushort* __restrict__ tsT,
                                               float* __restrict__ C2P) {
    __shared__ __align__(16) char lA[16384];
    __shared__ __align__(16) char lB[16384];
    const int tid = threadIdx.x;
    const int m0 = (blockIdx.x % 157) * 128;
    const int ks = blockIdx.x / 157;
    const int k0 = ks * 2048;
    const int lane = tid & 63, w = tid >> 6;
    const int wm = (w & 1) * 64, wn = (w >> 1) * 64;
    const int lrow = lane & 15, g16 = (lane >> 4) * 16;

    int awoff[4], bwoff[4];
    const uint4* pA[4];
    const uint4* pB[4];
#pragma unroll
    for (int c = 0; c < 4; ++c) {
        int lin = c * 256 + tid;
        int row = lin >> 3, ch = lin & 7;
        awoff[c] = row * 128 + ((ch * 16) ^ ((row & 7) << 4));
        bwoff[c] = awoff[c];
        pA[c] = (const uint4*)(Hb + (size_t)(m0 + row) * E + k0 + ch * 8);
        pB[c] = (const uint4*)(tsT + (size_t)row * E + k0 + ch * 8);
    }
    int aoff[4][2], boff[4][2];
#pragma unroll
    for (int f = 0; f < 4; ++f)
#pragma unroll
        for (int kk = 0; kk < 2; ++kk) {
            int ma = wm + f * 16 + lrow;
            aoff[f][kk] = ma * 128 + (((kk * 64) + g16) ^ ((ma & 7) << 4));
            int nb = wn + f * 16 + lrow;
            boff[f][kk] = nb * 128 + (((kk * 64) + g16) ^ ((nb & 7) << 4));
        }

    f32x4 zero4 = {0.f, 0.f, 0.f, 0.f};
    f32x4 acc[4][4];
#pragma unroll
    for (int i = 0; i < 4; ++i)
#pragma unroll
        for (int j = 0; j < 4; ++j) acc[i][j] = zero4;

    uint4 ra[4], rb[4];
#pragma unroll
    for (int c = 0; c < 4; ++c) { ra[c] = pA[c][0]; rb[c] = pB[c][0]; }

    for (int kt = 0; kt < 32; ++kt) {
        __syncthreads();
#pragma unroll
        for (int c = 0; c < 4; ++c) {
            *(uint4*)(lA + awoff[c]) = ra[c];
            *(uint4*)(lB + bwoff[c]) = rb[c];
        }
        __syncthreads();
        if (kt + 1 < 32) {
#pragma unroll
            for (int c = 0; c < 4; ++c) {
                pA[c] += 8; pB[c] += 8;
                ra[c] = pA[c][0]; rb[c] = pB[c][0];
            }
        }
#pragma unroll
        for (int kk = 0; kk < 2; ++kk) {
            bf16x8 av[4], bv[4];
#pragma unroll
            for (int f = 0; f < 4; ++f) av[f] = *(const bf16x8*)(lA + aoff[f][kk]);
#pragma unroll
            for (int f = 0; f < 4; ++f) bv[f] = *(const bf16x8*)(lB + boff[f][kk]);
#pragma unroll
            for (int i = 0; i < 4; ++i)
#pragma unroll
                for (int j = 0; j < 4; ++j)
                    acc[i][j] = __builtin_amdgcn_mfma_f32_16x16x32_bf16(av[i], bv[j], acc[i][j], 0, 0, 0);
        }
    }
    float* plane = C2P + (size_t)ks * NP2 * F;
    const int orow = (lane >> 4) * 4, ocol = lane & 15;
#pragma unroll
    for (int i = 0; i < 4; ++i)
#pragma unroll
        for (int j = 0; j < 4; ++j) {
            int gm = m0 + wm + i * 16 + orow;
            int gn = wn + j * 16 + ocol;
#pragma unroll
            for (int q = 0; q < 4; ++q)
                plane[(size_t)(gm + q) * F + gn] = acc[i][j][q];
        }
}

// ---------------- out = gelu(dvis[n] * sum_ks C2P[ks][n][f]) ----------------
__global__ void k_fin_out(const float* __restrict__ C2P, const float* __restrict__ dvis,
                          float* __restrict__ out) {
    int i4 = blockIdx.x * 256 + threadIdx.x;
    if (i4 < N * F / 4) {
        int n = i4 >> 5;
        float s = dvis[n];
        float4 v = make_float4(0.f, 0.f, 0.f, 0.f);
#pragma unroll
        for (int ks = 0; ks < KS_C; ++ks) {
            float4 p = reinterpret_cast<const float4*>(C2P + (size_t)ks * NP2 * F)[i4];
            v.x += p.x; v.y += p.y; v.z += p.z; v.w += p.w;
        }
        float4 o;
        o.x = gelu_erf(s * v.x);
        o.y = gelu_erf(s * v.y);
        o.z = gelu_erf(s * v.z);
        o.w = gelu_erf(s * v.w);
        reinterpret_cast<float4*>(out)[i4] = o;
    }
}

extern "C" void kernel_launch(void* const* d_in, const int* in_sizes, int n_in,
                              void* d_out, int out_size, void* d_ws, size_t ws_size,
                              hipStream_t stream) {
    const float* x     = (const float*)d_in[0];
    const float* H     = (const float*)d_in[1];
    const float* W     = (const float*)d_in[2];
    const float* lin_w = (const float*)d_in[3];
    const float* lin_b = (const float*)d_in[4];
    float* out = (float*)d_out;

    // workspace layout (bytes): ~440 MiB
    char* ws = (char*)d_ws;
    ushort* Hb  = (ushort*)ws;                                   // NP*E*2      = 335,544,320
    ushort* y   = (ushort*)(ws + 335544320);                     // NP*F*2      = 5,242,880
    ushort* yT  = (ushort*)(ws + 340787200);                     // F*NP*2      = 5,242,880
    float*  tB  = (float*) (ws + 346030080);                     // 8*E*F*4     = 33,554,432
    ushort* tsT = (ushort*)(ws + 379584512);                     // F*E*2       = 2,097,152
    float*  C2P = (float*) (ws + 381681664);                     // 4*NP2*F*4   = 41,156,608
    float*  DeP = (float*) (ws + 422838272);                     // 500*E*4     = 16,384,000
    float*  Dv  = (float*) (ws + 439222272);                     // N*4
    float*  dvis= (float*) (ws + 439302272);                     // N*4
    float*  se  = (float*) (ws + 439382272);                     // E*4
    float*  lwT = (float*) (ws + 439415040);                     // F*F*4

    // zero pads: Hb rows [N, NP), y rows [N, NP). No other init needed (all
    // partial planes are fully overwritten each call).
    hipMemsetAsync((char*)Hb + (size_t)N * E * 2, 0, (size_t)(NP - N) * E * 2, stream);
    hipMemsetAsync((char*)y + (size_t)N * F * 2, 0, (size_t)(NP - N) * F * 2, stream);

    k_transpose_lw<<<64, 256, 0, stream>>>(lin_w, lwT);
    k_prep<<<PREP_BLOCKS, 256, 0, stream>>>(H, Dv, DeP, Hb);
    k_fin_deg<<<(N + 255) / 256, 256, 0, stream>>>(Dv, DeP, W, dvis, se);
    k_xw<<<N / 4, 128, 0, stream>>>(x, lwT, lin_b, dvis, y);
    k_ytrans<<<(NP / 64) * 2, 256, 0, stream>>>(y, yT);
    k_gemmB<<<64 * KS_B, 256, 0, stream>>>(Hb, yT, tB);
    k_tst<<<(E / 64) * 2, 256, 0, stream>>>(tB, se, tsT);
    k_gemmC<<<157 * KS_C, 256, 0, stream>>>(Hb, tsT, C2P);
    k_fin_out<<<(N * F / 4 + 255) / 256, 256, 0, stream>>>(C2P, dvis, out);
}

// Round 5
// 704.429 us; speedup vs baseline: 2.4856x; 1.0245x over previous
//
#include <hip/hip_runtime.h>
#include <math.h>

static constexpr int N = 20000;       // nodes
static constexpr int E = 8192;        // hyperedges
static constexpr int F = 128;         // feature dim
static constexpr int NP = 20480;      // padded node count (K for gemmB; 512*40)
static constexpr int NP2 = 20096;     // padded node count for gemmC output planes (157*128)
static constexpr int PREP_BLOCKS = 500;   // blocks of k_prep that carry real rows (40 each)
static constexpr int KS_B = 8;        // gemmB split-K
static constexpr int KS_C = 4;        // gemmC split-K

typedef short bf16x8 __attribute__((ext_vector_type(8)));
typedef float f32x4 __attribute__((ext_vector_type(4)));

__device__ __forceinline__ float gelu_erf(float x) {
    return 0.5f * x * (1.0f + erff(x * 0.70710678118654752440f));
}
__device__ __forceinline__ ushort f2bf(float f) {
    unsigned u = __float_as_uint(f);
    return (ushort)((u + 0x7FFFu + ((u >> 16) & 1u)) >> 16);
}

// ---------------- lwT[k][f] = lin_w[f][k] ----------------
__global__ void k_transpose_lw(const float* __restrict__ lin_w, float* __restrict__ lwT) {
    int idx = blockIdx.x * 256 + threadIdx.x;
    if (idx < F * F) {
        int k = idx >> 7, f = idx & 127;
        lwT[idx] = lin_w[f * F + k];
    }
}

// ---------------- prep: stream H -> DeP (raw col partials), Hbs = bf16(dvis[v]*H[v][e]) ----
// grid 512 x 256; 40 rows per block. Blocks >= 500 write zero pad rows. NO atomics/memsets.
__global__ void k_prep(const float* __restrict__ H, float* __restrict__ DeP,
                       ushort* __restrict__ Hbs) {
    const int tid = threadIdx.x, lane = tid & 63, wid = tid >> 6;
    const int r0 = blockIdx.x * 40;
    if (r0 >= N) {            // pad rows [N, NP): Hbs = 0
        ushort4 z = make_ushort4(0, 0, 0, 0);
        for (int r = 0; r < 40; ++r) {
            ushort* orow = Hbs + (size_t)(r0 + r) * E;
#pragma unroll
            for (int j = 0; j < 8; ++j) *(ushort4*)(orow + j * 1024 + tid * 4) = z;
        }
        return;
    }
    __shared__ float rp[40][4];
    float4 ca[8];
#pragma unroll
    for (int j = 0; j < 8; ++j) ca[j] = make_float4(0.f, 0.f, 0.f, 0.f);
    float4 cur[8], nxt[8];
#pragma unroll
    for (int j = 0; j < 8; ++j) cur[j] = *(const float4*)(H + (size_t)r0 * E + j * 1024 + tid * 4);
    for (int r = 0; r < 40; ++r) {
        float rs = 0.f;
#pragma unroll
        for (int j = 0; j < 8; ++j) rs += (cur[j].x + cur[j].y) + (cur[j].z + cur[j].w);
#pragma unroll
        for (int off = 32; off > 0; off >>= 1) rs += __shfl_xor(rs, off, 64);
        if (lane == 0) rp[r][wid] = rs;
        if (r < 39) {
            const float* rowp = H + (size_t)(r0 + r + 1) * E;
#pragma unroll
            for (int j = 0; j < 8; ++j) nxt[j] = *(const float4*)(rowp + j * 1024 + tid * 4);
        }
        __syncthreads();
        float scale = rsqrtf(fmaxf(rp[r][0] + rp[r][1] + rp[r][2] + rp[r][3], 1.f));
        ushort* orow = Hbs + (size_t)(r0 + r) * E;
#pragma unroll
        for (int j = 0; j < 8; ++j) {
            ca[j].x += cur[j].x; ca[j].y += cur[j].y; ca[j].z += cur[j].z; ca[j].w += cur[j].w;
            ushort4 b;
            b.x = f2bf(cur[j].x * scale); b.y = f2bf(cur[j].y * scale);
            b.z = f2bf(cur[j].z * scale); b.w = f2bf(cur[j].w * scale);
            *(ushort4*)(orow + j * 1024 + tid * 4) = b;
        }
        if (r < 39) {
#pragma unroll
            for (int j = 0; j < 8; ++j) cur[j] = nxt[j];
        }
    }
    float* dp = DeP + (size_t)blockIdx.x * E;
#pragma unroll
    for (int j = 0; j < 8; ++j) *(float4*)(dp + j * 1024 + tid * 4) = ca[j];
}

// ---------------- se[e] = W[e] / clip(sum_p DeP[p][e], 1) ----------------
// grid 128 x 256: block handles 64 cols; 4-way p-split + LDS reduce.
__global__ void k_se(const float* __restrict__ DeP, const float* __restrict__ W,
                     float* __restrict__ se) {
    __shared__ float red[4][64];
    const int tid = threadIdx.x;
    const int c = blockIdx.x * 64 + (tid & 63);
    const int pg = tid >> 6;
    float s = 0.f;
#pragma unroll 5
    for (int p = pg; p < PREP_BLOCKS; p += 4) s += DeP[(size_t)p * E + c];
    red[pg][tid & 63] = s;
    __syncthreads();
    if (tid < 64) {
        float d = red[0][tid] + red[1][tid] + red[2][tid] + red[3][tid];
        int e = blockIdx.x * 64 + tid;
        se[e] = W[e] / fmaxf(d, 1.f);
    }
}

// ---------------- y[v][f] = bf16(x@lw^T + b)  (NO dvis; pad rows zeroed) ----------------
__global__ void k_xw(const float* __restrict__ x, const float* __restrict__ lwT,
                     const float* __restrict__ lin_b, ushort* __restrict__ y) {
    __shared__ __align__(16) float xs[4][F];
    int f = threadIdx.x;            // 128 threads
    int r0 = blockIdx.x * 4;
    if (r0 >= N) {
#pragma unroll
        for (int j = 0; j < 4; ++j) y[(size_t)(r0 + j) * F + f] = 0;
        return;
    }
#pragma unroll
    for (int j = 0; j < 4; ++j) xs[j][f] = x[(size_t)(r0 + j) * F + f];
    __syncthreads();
    float b = lin_b[f];
    float a0 = b, a1 = b, a2 = b, a3 = b;
#pragma unroll 4
    for (int k = 0; k < F; ++k) {
        float lw = lwT[k * F + f];
        a0 += xs[0][k] * lw;
        a1 += xs[1][k] * lw;
        a2 += xs[2][k] * lw;
        a3 += xs[3][k] * lw;
    }
    y[(size_t)(r0 + 0) * F + f] = f2bf(a0);
    y[(size_t)(r0 + 1) * F + f] = f2bf(a1);
    y[(size_t)(r0 + 2) * F + f] = f2bf(a2);
    y[(size_t)(r0 + 3) * F + f] = f2bf(a3);
}

// ---------------- yT[f][v] = y[v][f]  (bf16 64x64 tile transpose) ----------------
__global__ void k_ytrans(const ushort* __restrict__ y, ushort* __restrict__ yT) {
    __shared__ __align__(16) char tl[8192];
    int tid = threadIdx.x;
    int r0 = (blockIdx.x >> 1) * 64;   // v
    int c0 = (blockIdx.x & 1) * 64;    // f
#pragma unroll
    for (int c = 0; c < 2; ++c) {
        int lin = c * 256 + tid;
        int row = lin >> 3, ch = lin & 7;
        uint4 v = *(const uint4*)(y + (size_t)(r0 + row) * F + c0 + ch * 8);
        int key = ((row ^ (row >> 3)) & 7) << 4;
        *(uint4*)(tl + row * 128 + ((ch * 16) ^ key)) = v;
    }
    __syncthreads();
#pragma unroll
    for (int c = 0; c < 2; ++c) {
        int lin = c * 256 + tid;
        int fl = lin >> 3, vch = lin & 7;
        unsigned u[4];
#pragma unroll
        for (int qq = 0; qq < 4; ++qq) {
            int r1 = vch * 8 + qq * 2, r2 = r1 + 1;
            ushort a = *(const ushort*)(tl + r1 * 128 + ((fl * 2) ^ (((r1 ^ (r1 >> 3)) & 7) << 4)));
            ushort b = *(const ushort*)(tl + r2 * 128 + ((fl * 2) ^ (((r2 ^ (r2 >> 3)) & 7) << 4)));
            u[qq] = (unsigned)a | ((unsigned)b << 16);
        }
        uint4 o = make_uint4(u[0], u[1], u[2], u[3]);
        *(uint4*)(yT + (size_t)(c0 + fl) * NP + r0 + vch * 8) = o;
    }
}

// ---------------- tsT[f][e] = bf16(se[e] * sum_ks tB[ks][e][f])  (reduce + transpose) ------
__global__ void k_tst(const float* __restrict__ tB, const float* __restrict__ se,
                      ushort* __restrict__ tsT) {
    __shared__ __align__(16) char tl[8192];
    int tid = threadIdx.x;
    int r0 = (blockIdx.x >> 1) * 64;   // e
    int c0 = (blockIdx.x & 1) * 64;    // f
#pragma unroll
    for (int c = 0; c < 4; ++c) {
        int lin = c * 256 + tid;
        int row = lin >> 4, ch = lin & 15;
        size_t base = (size_t)(r0 + row) * F + c0 + ch * 4;
        float4 v = make_float4(0.f, 0.f, 0.f, 0.f);
#pragma unroll
        for (int ks = 0; ks < KS_B; ++ks) {
            float4 p = *(const float4*)(tB + (size_t)ks * E * F + base);
            v.x += p.x; v.y += p.y; v.z += p.z; v.w += p.w;
        }
        float s = se[r0 + row];
        ushort4 b;
        b.x = f2bf(v.x * s); b.y = f2bf(v.y * s); b.z = f2bf(v.z * s); b.w = f2bf(v.w * s);
        int key = ((row ^ (row >> 3)) & 7) << 4;
        *(ushort4*)(tl + row * 128 + ((ch * 8) ^ key)) = b;
    }
    __syncthreads();
#pragma unroll
    for (int c = 0; c < 2; ++c) {
        int lin = c * 256 + tid;
        int fl = lin >> 3, vch = lin & 7;
        unsigned u[4];
#pragma unroll
        for (int qq = 0; qq < 4; ++qq) {
            int r1 = vch * 8 + qq * 2, r2 = r1 + 1;
            ushort a = *(const ushort*)(tl + r1 * 128 + ((fl * 2) ^ (((r1 ^ (r1 >> 3)) & 7) << 4)));
            ushort b = *(const ushort*)(tl + r2 * 128 + ((fl * 2) ^ (((r2 ^ (r2 >> 3)) & 7) << 4)));
            u[qq] = (unsigned)a | ((unsigned)b << 16);
        }
        uint4 o = make_uint4(u[0], u[1], u[2], u[3]);
        *(uint4*)(tsT + (size_t)(c0 + fl) * E + r0 + vch * 8) = o;
    }
}

// ---------------- gemmB (MFMA): tB[ks][e][f] = sum_{v in chunk} Hbs[v][e] * yT[f][v] ------
__global__ __launch_bounds__(256) void k_gemmB(const ushort* __restrict__ Hbs,
                                               const ushort* __restrict__ yT,
                                               float* __restrict__ tB) {
    __shared__ __align__(16) char lA[16384];   // As[e 128][v 64] bf16, key ((e>>3)&7)<<4
    __shared__ __align__(16) char lB[16384];   // Bs[f 128][v 64] bf16, key (f&7)<<4
    const int tid = threadIdx.x;
    const int m0 = (blockIdx.x & 63) * 128;    // e tile
    const int ks = blockIdx.x >> 6;
    const int k0 = ks * 2560;                  // v chunk
    const int lane = tid & 63, w = tid >> 6;
    const int wm = (w & 1) * 64, wn = (w >> 1) * 64;
    const int lrow = lane & 15, g16 = (lane >> 4) * 16;

    const int vq = tid >> 4;
    const int e8 = (tid & 15) * 8;
    const ushort* pa = Hbs + (size_t)(k0 + vq * 4) * E + m0 + e8;
    const int abase = e8 * 128 + ((vq * 8) ^ ((tid & 7) << 4));

    int bwoff[4];
    const uint4* pb[4];
#pragma unroll
    for (int c = 0; c < 4; ++c) {
        int lin = c * 256 + tid;
        int row = lin >> 3, ch = lin & 7;
        bwoff[c] = row * 128 + ((ch * 16) ^ ((row & 7) << 4));
        pb[c] = (const uint4*)(yT + (size_t)row * NP + k0 + ch * 8);
    }
    int aoff[4][2], boff[4][2];
#pragma unroll
    for (int f = 0; f < 4; ++f)
#pragma unroll
        for (int kk = 0; kk < 2; ++kk) {
            int ma = wm + f * 16 + lrow;
            aoff[f][kk] = ma * 128 + (((kk * 64) + g16) ^ (((ma >> 3) & 7) << 4));
            int nb = wn + f * 16 + lrow;
            boff[f][kk] = nb * 128 + (((kk * 64) + g16) ^ ((nb & 7) << 4));
        }

    f32x4 zero4 = {0.f, 0.f, 0.f, 0.f};
    f32x4 acc[4][4];
#pragma unroll
    for (int i = 0; i < 4; ++i)
#pragma unroll
        for (int j = 0; j < 4; ++j) acc[i][j] = zero4;

    uint4 ra[4], rb[4];
#pragma unroll
    for (int r = 0; r < 4; ++r) ra[r] = *(const uint4*)(pa + (size_t)r * E);
#pragma unroll
    for (int c = 0; c < 4; ++c) rb[c] = pb[c][0];

    for (int kt = 0; kt < 40; ++kt) {
        __syncthreads();
        {
            const ushort* u0 = (const ushort*)&ra[0];
            const ushort* u1 = (const ushort*)&ra[1];
            const ushort* u2 = (const ushort*)&ra[2];
            const ushort* u3 = (const ushort*)&ra[3];
#pragma unroll
            for (int i = 0; i < 8; ++i) {
                uint2 wv;
                wv.x = (unsigned)u0[i] | ((unsigned)u1[i] << 16);
                wv.y = (unsigned)u2[i] | ((unsigned)u3[i] << 16);
                *(uint2*)(lA + abase + i * 128) = wv;
            }
        }
#pragma unroll
        for (int c = 0; c < 4; ++c) *(uint4*)(lB + bwoff[c]) = rb[c];
        __syncthreads();
        if (kt + 1 < 40) {
            pa += (size_t)64 * E;
#pragma unroll
            for (int r = 0; r < 4; ++r) ra[r] = *(const uint4*)(pa + (size_t)r * E);
#pragma unroll
            for (int c = 0; c < 4; ++c) { pb[c] += 8; rb[c] = pb[c][0]; }
        }
#pragma unroll
        for (int kk = 0; kk < 2; ++kk) {
            bf16x8 av[4], bv[4];
#pragma unroll
            for (int f = 0; f < 4; ++f) av[f] = *(const bf16x8*)(lA + aoff[f][kk]);
#pragma unroll
            for (int f = 0; f < 4; ++f) bv[f] = *(const bf16x8*)(lB + boff[f][kk]);
#pragma unroll
            for (int i = 0; i < 4; ++i)
#pragma unroll
                for (int j = 0; j < 4; ++j)
                    acc[i][j] = __builtin_amdgcn_mfma_f32_16x16x32_bf16(av[i], bv[j], acc[i][j], 0, 0, 0);
        }
    }
    float* plane = tB + (size_t)ks * E * F;
    const int orow = (lane >> 4) * 4, ocol = lane & 15;
#pragma unroll
    for (int i = 0; i < 4; ++i)
#pragma unroll
        for (int j = 0; j < 4; ++j) {
            int gm = m0 + wm + i * 16 + orow;
            int gn = wn + j * 16 + ocol;
#pragma unroll
            for (int q = 0; q < 4; ++q)
                plane[(size_t)(gm + q) * F + gn] = acc[i][j][q];
        }
}

// ---------------- gemmC (MFMA): C2P[ks][n][f] = sum_{e in chunk} Hbs[n][e] * tsT[f][e] -----
__global__ __launch_bounds__(256) void k_gemmC(const ushort* __restrict__ Hbs,
                                               const ushort* __restrict__ tsT,
                                               float* __restrict__ C2P) {
    __shared__ __align__(16) char lA[16384];
    __shared__ __align__(16) char lB[16384];
    const int tid = threadIdx.x;
    const int m0 = (blockIdx.x % 157) * 128;
    const int ks = blockIdx.x / 157;
    const int k0 = ks * 2048;
    const int lane = tid & 63, w = tid >> 6;
    const int wm = (w & 1) * 64, wn = (w >> 1) * 64;
    const int lrow = lane & 15, g16 = (lane >> 4) * 16;

    int awoff[4], bwoff[4];
    const uint4* pA[4];
    const uint4* pB[4];
#pragma unroll
    for (int c = 0; c < 4; ++c) {
        int lin = c * 256 + tid;
        int row = lin >> 3, ch = lin & 7;
        awoff[c] = row * 128 + ((ch * 16) ^ ((row & 7) << 4));
        bwoff[c] = awoff[c];
        pA[c] = (const uint4*)(Hbs + (size_t)(m0 + row) * E + k0 + ch * 8);
        pB[c] = (const uint4*)(tsT + (size_t)row * E + k0 + ch * 8);
    }
    int aoff[4][2], boff[4][2];
#pragma unroll
    for (int f = 0; f < 4; ++f)
#pragma unroll
        for (int kk = 0; kk < 2; ++kk) {
            int ma = wm + f * 16 + lrow;
            aoff[f][kk] = ma * 128 + (((kk * 64) + g16) ^ ((ma & 7) << 4));
            int nb = wn + f * 16 + lrow;
            boff[f][kk] = nb * 128 + (((kk * 64) + g16) ^ ((nb & 7) << 4));
        }

    f32x4 zero4 = {0.f, 0.f, 0.f, 0.f};
    f32x4 acc[4][4];
#pragma unroll
    for (int i = 0; i < 4; ++i)
#pragma unroll
        for (int j = 0; j < 4; ++j) acc[i][j] = zero4;

    uint4 ra[4], rb[4];
#pragma unroll
    for (int c = 0; c < 4; ++c) { ra[c] = pA[c][0]; rb[c] = pB[c][0]; }

    for (int kt = 0; kt < 32; ++kt) {
        __syncthreads();
#pragma unroll
        for (int c = 0; c < 4; ++c) {
            *(uint4*)(lA + awoff[c]) = ra[c];
            *(uint4*)(lB + bwoff[c]) = rb[c];
        }
        __syncthreads();
        if (kt + 1 < 32) {
#pragma unroll
            for (int c = 0; c < 4; ++c) {
                pA[c] += 8; pB[c] += 8;
                ra[c] = pA[c][0]; rb[c] = pB[c][0];
            }
        }
#pragma unroll
        for (int kk = 0; kk < 2; ++kk) {
            bf16x8 av[4], bv[4];
#pragma unroll
            for (int f = 0; f < 4; ++f) av[f] = *(const bf16x8*)(lA + aoff[f][kk]);
#pragma unroll
            for (int f = 0; f < 4; ++f) bv[f] = *(const bf16x8*)(lB + boff[f][kk]);
#pragma unroll
            for (int i = 0; i < 4; ++i)
#pragma unroll
                for (int j = 0; j < 4; ++j)
                    acc[i][j] = __builtin_amdgcn_mfma_f32_16x16x32_bf16(av[i], bv[j], acc[i][j], 0, 0, 0);
        }
    }
    float* plane = C2P + (size_t)ks * NP2 * F;
    const int orow = (lane >> 4) * 4, ocol = lane & 15;
#pragma unroll
    for (int i = 0; i < 4; ++i)
#pragma unroll
        for (int j = 0; j < 4; ++j) {
            int gm = m0 + wm + i * 16 + orow;
            int gn = wn + j * 16 + ocol;
#pragma unroll
            for (int q = 0; q < 4; ++q)
                plane[(size_t)(gm + q) * F + gn] = acc[i][j][q];
        }
}

// ---------------- out = gelu(sum_ks C2P[ks][n][f])   (dvis already folded into Hbs) --------
__global__ void k_fin_out(const float* __restrict__ C2P, float* __restrict__ out) {
    int i4 = blockIdx.x * 256 + threadIdx.x;
    if (i4 < N * F / 4) {
        float4 v = make_float4(0.f, 0.f, 0.f, 0.f);
#pragma unroll
        for (int ks = 0; ks < KS_C; ++ks) {
            float4 p = reinterpret_cast<const float4*>(C2P + (size_t)ks * NP2 * F)[i4];
            v.x += p.x; v.y += p.y; v.z += p.z; v.w += p.w;
        }
        float4 o;
        o.x = gelu_erf(v.x);
        o.y = gelu_erf(v.y);
        o.z = gelu_erf(v.z);
        o.w = gelu_erf(v.w);
        reinterpret_cast<float4*>(out)[i4] = o;
    }
}

extern "C" void kernel_launch(void* const* d_in, const int* in_sizes, int n_in,
                              void* d_out, int out_size, void* d_ws, size_t ws_size,
                              hipStream_t stream) {
    const float* x     = (const float*)d_in[0];
    const float* H     = (const float*)d_in[1];
    const float* W     = (const float*)d_in[2];
    const float* lin_w = (const float*)d_in[3];
    const float* lin_b = (const float*)d_in[4];
    float* out = (float*)d_out;

    // workspace layout (bytes): ~439 MiB
    char* ws = (char*)d_ws;
    ushort* Hbs = (ushort*)ws;                                   // NP*E*2      = 335,544,320
    ushort* y   = (ushort*)(ws + 335544320);                     // NP*F*2      = 5,242,880
    ushort* yT  = (ushort*)(ws + 340787200);                     // F*NP*2      = 5,242,880
    float*  tB  = (float*) (ws + 346030080);                     // 8*E*F*4     = 33,554,432
    ushort* tsT = (ushort*)(ws + 379584512);                     // F*E*2       = 2,097,152
    float*  C2P = (float*) (ws + 381681664);                     // 4*NP2*F*4   = 41,156,608
    float*  DeP = (float*) (ws + 422838272);                     // 500*E*4     = 16,384,000
    float*  se  = (float*) (ws + 439222272);                     // E*4
    float*  lwT = (float*) (ws + 439255040);                     // F*F*4

    k_transpose_lw<<<64, 256, 0, stream>>>(lin_w, lwT);
    k_xw<<<NP / 4, 128, 0, stream>>>(x, lwT, lin_b, y);
    k_ytrans<<<(NP / 64) * 2, 256, 0, stream>>>(y, yT);
    k_prep<<<NP / 40, 256, 0, stream>>>(H, DeP, Hbs);
    k_se<<<E / 64, 256, 0, stream>>>(DeP, W, se);
    k_gemmB<<<64 * KS_B, 256, 0, stream>>>(Hbs, yT, tB);
    k_tst<<<(E / 64) * 2, 256, 0, stream>>>(tB, se, tsT);
    k_gemmC<<<157 * KS_C, 256, 0, stream>>>(Hbs, tsT, C2P);
    k_fin_out<<<(N * F / 4 + 255) / 256, 256, 0, stream>>>(C2P, out);
}

// Round 6
// 623.495 us; speedup vs baseline: 2.8083x; 1.1298x over previous
//
#include <hip/hip_runtime.h>
#include <math.h>

static constexpr int N = 20000;       // nodes
static constexpr int E = 8192;        // hyperedges
static constexpr int F = 128;         // feature dim
static constexpr int NP = 20480;      // padded node count (K for gemmB; 1024*20)
static constexpr int NP2 = 20096;     // padded node count for gemmC output planes (157*128)
static constexpr int PREP_REAL = 1000;    // blocks of k_prep carrying real rows (20 each)
static constexpr int KS_B = 8;        // gemmB split-K
static constexpr int KS_C = 4;        // gemmC split-K

typedef short bf16x8 __attribute__((ext_vector_type(8)));
typedef float f32x4 __attribute__((ext_vector_type(4)));

__device__ __forceinline__ float gelu_erf(float x) {
    return 0.5f * x * (1.0f + erff(x * 0.70710678118654752440f));
}
__device__ __forceinline__ ushort f2bf(float f) {
    unsigned u = __float_as_uint(f);
    return (ushort)((u + 0x7FFFu + ((u >> 16) & 1u)) >> 16);
}

// ---------------- lwT[k][f] = lin_w[f][k] ----------------
__global__ void k_transpose_lw(const float* __restrict__ lin_w, float* __restrict__ lwT) {
    int idx = blockIdx.x * 256 + threadIdx.x;
    if (idx < F * F) {
        int k = idx >> 7, f = idx & 127;
        lwT[idx] = lin_w[f * F + k];
    }
}

// ---------------- prep: stream H -> DeP (raw col partials), Hbs = bf16(dvis[v]*H[v][e]) ----
// grid 1024 x 256; 20 rows per block (4 blocks/CU for latency hiding). NO atomics/memsets.
__global__ void k_prep(const float* __restrict__ H, float* __restrict__ DeP,
                       ushort* __restrict__ Hbs) {
    const int tid = threadIdx.x, lane = tid & 63, wid = tid >> 6;
    const int r0 = blockIdx.x * 20;
    if (r0 >= N) {            // pad rows [N, NP): Hbs = 0
        ushort4 z = make_ushort4(0, 0, 0, 0);
        for (int r = 0; r < 20; ++r) {
            ushort* orow = Hbs + (size_t)(r0 + r) * E;
#pragma unroll
            for (int j = 0; j < 8; ++j) *(ushort4*)(orow + j * 1024 + tid * 4) = z;
        }
        return;
    }
    __shared__ float rp[20][4];
    float4 ca[8];
#pragma unroll
    for (int j = 0; j < 8; ++j) ca[j] = make_float4(0.f, 0.f, 0.f, 0.f);
    float4 cur[8], nxt[8];
#pragma unroll
    for (int j = 0; j < 8; ++j) cur[j] = *(const float4*)(H + (size_t)r0 * E + j * 1024 + tid * 4);
    for (int r = 0; r < 20; ++r) {
        float rs = 0.f;
#pragma unroll
        for (int j = 0; j < 8; ++j) rs += (cur[j].x + cur[j].y) + (cur[j].z + cur[j].w);
#pragma unroll
        for (int off = 32; off > 0; off >>= 1) rs += __shfl_xor(rs, off, 64);
        if (lane == 0) rp[r][wid] = rs;
        if (r < 19) {
            const float* rowp = H + (size_t)(r0 + r + 1) * E;
#pragma unroll
            for (int j = 0; j < 8; ++j) nxt[j] = *(const float4*)(rowp + j * 1024 + tid * 4);
        }
        __syncthreads();
        float scale = rsqrtf(fmaxf(rp[r][0] + rp[r][1] + rp[r][2] + rp[r][3], 1.f));
        ushort* orow = Hbs + (size_t)(r0 + r) * E;
#pragma unroll
        for (int j = 0; j < 8; ++j) {
            ca[j].x += cur[j].x; ca[j].y += cur[j].y; ca[j].z += cur[j].z; ca[j].w += cur[j].w;
            ushort4 b;
            b.x = f2bf(cur[j].x * scale); b.y = f2bf(cur[j].y * scale);
            b.z = f2bf(cur[j].z * scale); b.w = f2bf(cur[j].w * scale);
            *(ushort4*)(orow + j * 1024 + tid * 4) = b;
        }
        if (r < 19) {
#pragma unroll
            for (int j = 0; j < 8; ++j) cur[j] = nxt[j];
        }
    }
    float* dp = DeP + (size_t)blockIdx.x * E;
#pragma unroll
    for (int j = 0; j < 8; ++j) *(float4*)(dp + j * 1024 + tid * 4) = ca[j];
}

// ---------------- se[e] = W[e] / clip(sum_p DeP[p][e], 1) ----------------
__global__ void k_se(const float* __restrict__ DeP, const float* __restrict__ W,
                     float* __restrict__ se) {
    __shared__ float red[4][64];
    const int tid = threadIdx.x;
    const int c = blockIdx.x * 64 + (tid & 63);
    const int pg = tid >> 6;
    float s = 0.f;
    for (int p = pg; p < PREP_REAL; p += 4) s += DeP[(size_t)p * E + c];
    red[pg][tid & 63] = s;
    __syncthreads();
    if (tid < 64) {
        float d = red[0][tid] + red[1][tid] + red[2][tid] + red[3][tid];
        int e = blockIdx.x * 64 + tid;
        se[e] = W[e] / fmaxf(d, 1.f);
    }
}

// ---------------- y[v][f] = bf16(x@lw^T + b)  (pad rows zeroed) ----------------
__global__ void k_xw(const float* __restrict__ x, const float* __restrict__ lwT,
                     const float* __restrict__ lin_b, ushort* __restrict__ y) {
    __shared__ __align__(16) float xs[4][F];
    int f = threadIdx.x;            // 128 threads
    int r0 = blockIdx.x * 4;
    if (r0 >= N) {
#pragma unroll
        for (int j = 0; j < 4; ++j) y[(size_t)(r0 + j) * F + f] = 0;
        return;
    }
#pragma unroll
    for (int j = 0; j < 4; ++j) xs[j][f] = x[(size_t)(r0 + j) * F + f];
    __syncthreads();
    float b = lin_b[f];
    float a0 = b, a1 = b, a2 = b, a3 = b;
#pragma unroll 4
    for (int k = 0; k < F; ++k) {
        float lw = lwT[k * F + f];
        a0 += xs[0][k] * lw;
        a1 += xs[1][k] * lw;
        a2 += xs[2][k] * lw;
        a3 += xs[3][k] * lw;
    }
    y[(size_t)(r0 + 0) * F + f] = f2bf(a0);
    y[(size_t)(r0 + 1) * F + f] = f2bf(a1);
    y[(size_t)(r0 + 2) * F + f] = f2bf(a2);
    y[(size_t)(r0 + 3) * F + f] = f2bf(a3);
}

// ---------------- yT[f][v] = y[v][f]  (bf16 64x64 tile transpose) ----------------
__global__ void k_ytrans(const ushort* __restrict__ y, ushort* __restrict__ yT) {
    __shared__ __align__(16) char tl[8192];
    int tid = threadIdx.x;
    int r0 = (blockIdx.x >> 1) * 64;   // v
    int c0 = (blockIdx.x & 1) * 64;    // f
#pragma unroll
    for (int c = 0; c < 2; ++c) {
        int lin = c * 256 + tid;
        int row = lin >> 3, ch = lin & 7;
        uint4 v = *(const uint4*)(y + (size_t)(r0 + row) * F + c0 + ch * 8);
        int key = ((row ^ (row >> 3)) & 7) << 4;
        *(uint4*)(tl + row * 128 + ((ch * 16) ^ key)) = v;
    }
    __syncthreads();
#pragma unroll
    for (int c = 0; c < 2; ++c) {
        int lin = c * 256 + tid;
        int fl = lin >> 3, vch = lin & 7;
        unsigned u[4];
#pragma unroll
        for (int qq = 0; qq < 4; ++qq) {
            int r1 = vch * 8 + qq * 2, r2 = r1 + 1;
            ushort a = *(const ushort*)(tl + r1 * 128 + ((fl * 2) ^ (((r1 ^ (r1 >> 3)) & 7) << 4)));
            ushort b = *(const ushort*)(tl + r2 * 128 + ((fl * 2) ^ (((r2 ^ (r2 >> 3)) & 7) << 4)));
            u[qq] = (unsigned)a | ((unsigned)b << 16);
        }
        uint4 o = make_uint4(u[0], u[1], u[2], u[3]);
        *(uint4*)(yT + (size_t)(c0 + fl) * NP + r0 + vch * 8) = o;
    }
}

// ---------------- tsT[f][e] = bf16(se[e] * sum_ks tB[ks][e][f])  (reduce + transpose) ------
__global__ void k_tst(const float* __restrict__ tB, const float* __restrict__ se,
                      ushort* __restrict__ tsT) {
    __shared__ __align__(16) char tl[8192];
    int tid = threadIdx.x;
    int r0 = (blockIdx.x >> 1) * 64;   // e
    int c0 = (blockIdx.x & 1) * 64;    // f
#pragma unroll
    for (int c = 0; c < 4; ++c) {
        int lin = c * 256 + tid;
        int row = lin >> 4, ch = lin & 15;
        size_t base = (size_t)(r0 + row) * F + c0 + ch * 4;
        float4 v = make_float4(0.f, 0.f, 0.f, 0.f);
#pragma unroll
        for (int ks = 0; ks < KS_B; ++ks) {
            float4 p = *(const float4*)(tB + (size_t)ks * E * F + base);
            v.x += p.x; v.y += p.y; v.z += p.z; v.w += p.w;
        }
        float s = se[r0 + row];
        ushort4 b;
        b.x = f2bf(v.x * s); b.y = f2bf(v.y * s); b.z = f2bf(v.z * s); b.w = f2bf(v.w * s);
        int key = ((row ^ (row >> 3)) & 7) << 4;
        *(ushort4*)(tl + row * 128 + ((ch * 8) ^ key)) = b;
    }
    __syncthreads();
#pragma unroll
    for (int c = 0; c < 2; ++c) {
        int lin = c * 256 + tid;
        int fl = lin >> 3, vch = lin & 7;
        unsigned u[4];
#pragma unroll
        for (int qq = 0; qq < 4; ++qq) {
            int r1 = vch * 8 + qq * 2, r2 = r1 + 1;
            ushort a = *(const ushort*)(tl + r1 * 128 + ((fl * 2) ^ (((r1 ^ (r1 >> 3)) & 7) << 4)));
            ushort b = *(const ushort*)(tl + r2 * 128 + ((fl * 2) ^ (((r2 ^ (r2 >> 3)) & 7) << 4)));
            u[qq] = (unsigned)a | ((unsigned)b << 16);
        }
        uint4 o = make_uint4(u[0], u[1], u[2], u[3]);
        *(uint4*)(tsT + (size_t)(c0 + fl) * E + r0 + vch * 8) = o;
    }
}

// ---------------- gemmB (MFMA): tB[ks][e][f] = sum_{v in chunk} Hbs[v][e] * yT[f][v] ------
// Double-buffered LDS, ONE barrier per K-step.
__global__ __launch_bounds__(256) void k_gemmB(const ushort* __restrict__ Hbs,
                                               const ushort* __restrict__ yT,
                                               float* __restrict__ tB) {
    __shared__ __align__(16) char lA[2][16384];   // As[e 128][v 64] bf16, key ((e>>3)&7)<<4
    __shared__ __align__(16) char lB[2][16384];   // Bs[f 128][v 64] bf16, key (f&7)<<4
    const int tid = threadIdx.x;
    const int m0 = (blockIdx.x & 63) * 128;    // e tile
    const int ks = blockIdx.x >> 6;
    const int k0 = ks * 2560;                  // v chunk
    const int lane = tid & 63, w = tid >> 6;
    const int wm = (w & 1) * 64, wn = (w >> 1) * 64;
    const int lrow = lane & 15, g16 = (lane >> 4) * 16;
    const int NSTEP = 40;

    const int vq = tid >> 4;
    const int e8 = (tid & 15) * 8;
    const ushort* pa = Hbs + (size_t)(k0 + vq * 4) * E + m0 + e8;
    const int abase = e8 * 128 + ((vq * 8) ^ ((tid & 7) << 4));

    int bwoff[4];
    const uint4* pb[4];
#pragma unroll
    for (int c = 0; c < 4; ++c) {
        int lin = c * 256 + tid;
        int row = lin >> 3, ch = lin & 7;
        bwoff[c] = row * 128 + ((ch * 16) ^ ((row & 7) << 4));
        pb[c] = (const uint4*)(yT + (size_t)row * NP + k0 + ch * 8);
    }
    int aoff[4][2], boff[4][2];
#pragma unroll
    for (int f = 0; f < 4; ++f)
#pragma unroll
        for (int kk = 0; kk < 2; ++kk) {
            int ma = wm + f * 16 + lrow;
            aoff[f][kk] = ma * 128 + (((kk * 64) + g16) ^ (((ma >> 3) & 7) << 4));
            int nb = wn + f * 16 + lrow;
            boff[f][kk] = nb * 128 + (((kk * 64) + g16) ^ ((nb & 7) << 4));
        }

    f32x4 zero4 = {0.f, 0.f, 0.f, 0.f};
    f32x4 acc[4][4];
#pragma unroll
    for (int i = 0; i < 4; ++i)
#pragma unroll
        for (int j = 0; j < 4; ++j) acc[i][j] = zero4;

    uint4 ra[4], rb[4];
    // prologue: tile0 -> regs -> buf0; tile1 -> regs
#pragma unroll
    for (int r = 0; r < 4; ++r) ra[r] = *(const uint4*)(pa + (size_t)r * E);
#pragma unroll
    for (int c = 0; c < 4; ++c) rb[c] = pb[c][0];
    {
        const ushort* u0 = (const ushort*)&ra[0];
        const ushort* u1 = (const ushort*)&ra[1];
        const ushort* u2 = (const ushort*)&ra[2];
        const ushort* u3 = (const ushort*)&ra[3];
#pragma unroll
        for (int i = 0; i < 8; ++i) {
            uint2 wv;
            wv.x = (unsigned)u0[i] | ((unsigned)u1[i] << 16);
            wv.y = (unsigned)u2[i] | ((unsigned)u3[i] << 16);
            *(uint2*)(lA[0] + abase + i * 128) = wv;
        }
#pragma unroll
        for (int c = 0; c < 4; ++c) *(uint4*)(lB[0] + bwoff[c]) = rb[c];
    }
    pa += (size_t)64 * E;
#pragma unroll
    for (int r = 0; r < 4; ++r) ra[r] = *(const uint4*)(pa + (size_t)r * E);
#pragma unroll
    for (int c = 0; c < 4; ++c) { pb[c] += 8; rb[c] = pb[c][0]; }
    __syncthreads();

    for (int kt = 0; kt < NSTEP; ++kt) {
        const int cur = kt & 1;
        if (kt + 1 < NSTEP) {
            // write tile kt+1 into buf cur^1
            const ushort* u0 = (const ushort*)&ra[0];
            const ushort* u1 = (const ushort*)&ra[1];
            const ushort* u2 = (const ushort*)&ra[2];
            const ushort* u3 = (const ushort*)&ra[3];
#pragma unroll
            for (int i = 0; i < 8; ++i) {
                uint2 wv;
                wv.x = (unsigned)u0[i] | ((unsigned)u1[i] << 16);
                wv.y = (unsigned)u2[i] | ((unsigned)u3[i] << 16);
                *(uint2*)(lA[cur ^ 1] + abase + i * 128) = wv;
            }
#pragma unroll
            for (int c = 0; c < 4; ++c) *(uint4*)(lB[cur ^ 1] + bwoff[c]) = rb[c];
        }
        if (kt + 2 < NSTEP) {
            pa += (size_t)64 * E;
#pragma unroll
            for (int r = 0; r < 4; ++r) ra[r] = *(const uint4*)(pa + (size_t)r * E);
#pragma unroll
            for (int c = 0; c < 4; ++c) { pb[c] += 8; rb[c] = pb[c][0]; }
        }
#pragma unroll
        for (int kk = 0; kk < 2; ++kk) {
            bf16x8 av[4], bv[4];
#pragma unroll
            for (int f = 0; f < 4; ++f) av[f] = *(const bf16x8*)(lA[cur] + aoff[f][kk]);
#pragma unroll
            for (int f = 0; f < 4; ++f) bv[f] = *(const bf16x8*)(lB[cur] + boff[f][kk]);
#pragma unroll
            for (int i = 0; i < 4; ++i)
#pragma unroll
                for (int j = 0; j < 4; ++j)
                    acc[i][j] = __builtin_amdgcn_mfma_f32_16x16x32_bf16(av[i], bv[j], acc[i][j], 0, 0, 0);
        }
        if (kt + 1 < NSTEP) __syncthreads();
    }
    float* plane = tB + (size_t)ks * E * F;
    const int orow = (lane >> 4) * 4, ocol = lane & 15;
#pragma unroll
    for (int i = 0; i < 4; ++i)
#pragma unroll
        for (int j = 0; j < 4; ++j) {
            int gm = m0 + wm + i * 16 + orow;
            int gn = wn + j * 16 + ocol;
#pragma unroll
            for (int q = 0; q < 4; ++q)
                plane[(size_t)(gm + q) * F + gn] = acc[i][j][q];
        }
}

// ---------------- gemmC (MFMA): C2P[ks][n][f] = sum_{e in chunk} Hbs[n][e] * tsT[f][e] -----
// Double-buffered LDS, ONE barrier per K-step.
__global__ __launch_bounds__(256) void k_gemmC(const ushort* __restrict__ Hbs,
                                               const ushort* __restrict__ tsT,
                                               float* __restrict__ C2P) {
    __shared__ __align__(16) char lA[2][16384];
    __shared__ __align__(16) char lB[2][16384];
    const int tid = threadIdx.x;
    const int m0 = (blockIdx.x % 157) * 128;
    const int ks = blockIdx.x / 157;
    const int k0 = ks * 2048;
    const int lane = tid & 63, w = tid >> 6;
    const int wm = (w & 1) * 64, wn = (w >> 1) * 64;
    const int lrow = lane & 15, g16 = (lane >> 4) * 16;
    const int NSTEP = 32;

    int awoff[4], bwoff[4];
    const uint4* pA[4];
    const uint4* pB[4];
#pragma unroll
    for (int c = 0; c < 4; ++c) {
        int lin = c * 256 + tid;
        int row = lin >> 3, ch = lin & 7;
        awoff[c] = row * 128 + ((ch * 16) ^ ((row & 7) << 4));
        bwoff[c] = awoff[c];
        pA[c] = (const uint4*)(Hbs + (size_t)(m0 + row) * E + k0 + ch * 8);
        pB[c] = (const uint4*)(tsT + (size_t)row * E + k0 + ch * 8);
    }
    int aoff[4][2], boff[4][2];
#pragma unroll
    for (int f = 0; f < 4; ++f)
#pragma unroll
        for (int kk = 0; kk < 2; ++kk) {
            int ma = wm + f * 16 + lrow;
            aoff[f][kk] = ma * 128 + (((kk * 64) + g16) ^ ((ma & 7) << 4));
            int nb = wn + f * 16 + lrow;
            boff[f][kk] = nb * 128 + (((kk * 64) + g16) ^ ((nb & 7) << 4));
        }

    f32x4 zero4 = {0.f, 0.f, 0.f, 0.f};
    f32x4 acc[4][4];
#pragma unroll
    for (int i = 0; i < 4; ++i)
#pragma unroll
        for (int j = 0; j < 4; ++j) acc[i][j] = zero4;

    uint4 ra[4], rb[4];
#pragma unroll
    for (int c = 0; c < 4; ++c) { ra[c] = pA[c][0]; rb[c] = pB[c][0]; }
#pragma unroll
    for (int c = 0; c < 4; ++c) {
        *(uint4*)(lA[0] + awoff[c]) = ra[c];
        *(uint4*)(lB[0] + bwoff[c]) = rb[c];
    }
#pragma unroll
    for (int c = 0; c < 4; ++c) {
        pA[c] += 8; pB[c] += 8;
        ra[c] = pA[c][0]; rb[c] = pB[c][0];
    }
    __syncthreads();

    for (int kt = 0; kt < NSTEP; ++kt) {
        const int cur = kt & 1;
        if (kt + 1 < NSTEP) {
#pragma unroll
            for (int c = 0; c < 4; ++c) {
                *(uint4*)(lA[cur ^ 1] + awoff[c]) = ra[c];
                *(uint4*)(lB[cur ^ 1] + bwoff[c]) = rb[c];
            }
        }
        if (kt + 2 < NSTEP) {
#pragma unroll
            for (int c = 0; c < 4; ++c) {
                pA[c] += 8; pB[c] += 8;
                ra[c] = pA[c][0]; rb[c] = pB[c][0];
            }
        }
#pragma unroll
        for (int kk = 0; kk < 2; ++kk) {
            bf16x8 av[4], bv[4];
#pragma unroll
            for (int f = 0; f < 4; ++f) av[f] = *(const bf16x8*)(lA[cur] + aoff[f][kk]);
#pragma unroll
            for (int f = 0; f < 4; ++f) bv[f] = *(const bf16x8*)(lB[cur] + boff[f][kk]);
#pragma unroll
            for (int i = 0; i < 4; ++i)
#pragma unroll
                for (int j = 0; j < 4; ++j)
                    acc[i][j] = __builtin_amdgcn_mfma_f32_16x16x32_bf16(av[i], bv[j], acc[i][j], 0, 0, 0);
        }
        if (kt + 1 < NSTEP) __syncthreads();
    }
    float* plane = C2P + (size_t)ks * NP2 * F;
    const int orow = (lane >> 4) * 4, ocol = lane & 15;
#pragma unroll
    for (int i = 0; i < 4; ++i)
#pragma unroll
        for (int j = 0; j < 4; ++j) {
            int gm = m0 + wm + i * 16 + orow;
            int gn = wn + j * 16 + ocol;
#pragma unroll
            for (int q = 0; q < 4; ++q)
                plane[(size_t)(gm + q) * F + gn] = acc[i][j][q];
        }
}

// ---------------- out = gelu(sum_ks C2P[ks][n][f]) ----------------
__global__ void k_fin_out(const float* __restrict__ C2P, float* __restrict__ out) {
    int i4 = blockIdx.x * 256 + threadIdx.x;
    if (i4 < N * F / 4) {
        float4 v = make_float4(0.f, 0.f, 0.f, 0.f);
#pragma unroll
        for (int ks = 0; ks < KS_C; ++ks) {
            float4 p = reinterpret_cast<const float4*>(C2P + (size_t)ks * NP2 * F)[i4];
            v.x += p.x; v.y += p.y; v.z += p.z; v.w += p.w;
        }
        float4 o;
        o.x = gelu_erf(v.x);
        o.y = gelu_erf(v.y);
        o.z = gelu_erf(v.z);
        o.w = gelu_erf(v.w);
        reinterpret_cast<float4*>(out)[i4] = o;
    }
}

extern "C" void kernel_launch(void* const* d_in, const int* in_sizes, int n_in,
                              void* d_out, int out_size, void* d_ws, size_t ws_size,
                              hipStream_t stream) {
    const float* x     = (const float*)d_in[0];
    const float* H     = (const float*)d_in[1];
    const float* W     = (const float*)d_in[2];
    const float* lin_w = (const float*)d_in[3];
    const float* lin_b = (const float*)d_in[4];
    float* out = (float*)d_out;

    // workspace layout (bytes): ~456 MiB
    char* ws = (char*)d_ws;
    ushort* Hbs = (ushort*)ws;                                   // NP*E*2      = 335,544,320
    ushort* y   = (ushort*)(ws + 335544320);                     // NP*F*2      = 5,242,880
    ushort* yT  = (ushort*)(ws + 340787200);                     // F*NP*2      = 5,242,880
    float*  tB  = (float*) (ws + 346030080);                     // 8*E*F*4     = 33,554,432
    ushort* tsT = (ushort*)(ws + 379584512);                     // F*E*2       = 2,097,152
    float*  C2P = (float*) (ws + 381681664);                     // 4*NP2*F*4   = 41,156,608
    float*  DeP = (float*) (ws + 422838272);                     // 1024*E*4    = 33,554,432
    float*  se  = (float*) (ws + 456392704);                     // E*4
    float*  lwT = (float*) (ws + 456425472);                     // F*F*4

    k_transpose_lw<<<64, 256, 0, stream>>>(lin_w, lwT);
    k_xw<<<NP / 4, 128, 0, stream>>>(x, lwT, lin_b, y);
    k_ytrans<<<(NP / 64) * 2, 256, 0, stream>>>(y, yT);
    k_prep<<<NP / 20, 256, 0, stream>>>(H, DeP, Hbs);
    k_se<<<E / 64, 256, 0, stream>>>(DeP, W, se);
    k_gemmB<<<64 * KS_B, 256, 0, stream>>>(Hbs, yT, tB);
    k_tst<<<(E / 64) * 2, 256, 0, stream>>>(tB, se, tsT);
    k_gemmC<<<157 * KS_C, 256, 0, stream>>>(Hbs, tsT, C2P);
    k_fin_out<<<(N * F / 4 + 255) / 256, 256, 0, stream>>>(C2P, out);
}